// Round 4
// baseline (788.243 us; speedup 1.0000x reference)
//
#include <hip/hip_runtime.h>
#include <hip/hip_bf16.h>
#include <math.h>

typedef unsigned short ushort_t;
typedef float f32x4 __attribute__((ext_vector_type(4)));
typedef short bf16x8v __attribute__((ext_vector_type(8)));

static constexpr float SP_BIAS = 0.5413248546129181f; // log(expm1(1.0))
#define MAXB 1024   // max buckets (supports N <= 131072, matches 17-bit src pack)

__device__ __forceinline__ ushort_t f2bf(float f) {
    union { float f; unsigned u; } v; v.f = f;
    unsigned r = v.u + 0x7FFFu + ((v.u >> 16) & 1u);   // RNE
    return (ushort_t)(r >> 16);
}
__device__ __forceinline__ float bf2f(ushort_t u) {
    union { unsigned u; float f; } v; v.u = ((unsigned)u) << 16;
    return v.f;
}

// ---------------------------------------------------------------------------
// Detect int32 vs int64 edge_index layout. is32 pre-zeroed; set 1 if any odd
// int32 word nonzero (-> genuine int32 pairs, not int64 low-words).
__global__ void k_detect(const int* __restrict__ ei32, int n_check,
                         int* __restrict__ is32) {
    int idx = blockIdx.x * 256 + threadIdx.x;
    int found = 0;
    for (int i = idx; i < n_check; i += 2048) {
        if (ei32[2 * i + 1] != 0) { found = 1; break; }
    }
    if (found) atomicOr(is32, 1);
}

// ---------------------------------------------------------------------------
// h_bf = bf16(x @ W1 + b1); 4 nodes/block, thread t of wave g -> feature t.
__global__ __launch_bounds__(256) void k_lin1(const float* __restrict__ x,
                                              const float* __restrict__ W1,
                                              const float* __restrict__ b1,
                                              ushort_t* __restrict__ h_bf, int N) {
    __shared__ float Ws[27 * 64];
    __shared__ float bs[64];
    __shared__ float xs[4 * 27];
    int tid = threadIdx.x;
    for (int i = tid; i < 27 * 64; i += 256) Ws[i] = W1[i];
    if (tid < 64) bs[tid] = b1[tid];
    int base = blockIdx.x * 4;
    if (tid < 108) {
        int gidx = base * 27 + tid;
        xs[tid] = (gidx < N * 27) ? x[gidx] : 0.f;
    }
    __syncthreads();
    int g = tid >> 6, t = tid & 63;
    int node = base + g;
    if (node < N) {
        float acc = bs[t];
        const float* xr = &xs[g * 27];
#pragma unroll
        for (int k = 0; k < 27; ++k) acc = fmaf(xr[k], Ws[k * 64 + t], acc);
        h_bf[(size_t)node * 64 + t] = f2bf(acc);
    }
}

// ---------------------------------------------------------------------------
// Bin edges into B buckets of 128 consecutive dst each. Per block (4096
// edges): LDS hist -> reserve contiguous runs via one global atomicAdd per
// nonempty bucket -> write packed (dst_local<<17)|src into the run.
__global__ __launch_bounds__(256) void k_bin(const int* __restrict__ ei,
                                             const int* __restrict__ is32,
                                             int* __restrict__ bucketCnt,
                                             int* __restrict__ bucketArr,
                                             int E, int B, int CAP) {
    __shared__ int hist[MAXB];
    __shared__ int cur[MAXB];
    int tid = threadIdx.x;
    for (int i = tid; i < B; i += 256) hist[i] = 0;
    __syncthreads();
    int e0 = blockIdx.x * 4096;
    int mode32 = *is32;
    // pass 1: count
#pragma unroll
    for (int k = 0; k < 16; ++k) {
        int e = e0 + k * 256 + tid;
        if (e < E) {
            int dst = mode32 ? ei[E + e] : ((const int2*)ei)[E + e].x;
            atomicAdd(&hist[dst >> 7], 1);
        }
    }
    __syncthreads();
    // reserve runs
    for (int b = tid; b < B; b += 256) {
        int c = hist[b];
        if (c > 0) {
            int base = atomicAdd(&bucketCnt[b], c);
            cur[b] = b * CAP + base;
        }
    }
    __syncthreads();
    // pass 2: place (edge re-read hits L2/L3)
#pragma unroll
    for (int k = 0; k < 16; ++k) {
        int e = e0 + k * 256 + tid;
        if (e < E) {
            int src, dst;
            if (mode32) { src = ei[e]; dst = ei[E + e]; }
            else { src = ((const int2*)ei)[e].x; dst = ((const int2*)ei)[E + e].x; }
            int b = dst >> 7;
            int slot = atomicAdd(&cur[b], 1);
            if (slot < (b + 1) * CAP)
                bucketArr[slot] = ((dst & 127) << 17) | src;
        }
    }
}

// ---------------------------------------------------------------------------
// One block per bucket: fp32 LDS accumulator [128 dst x 64 feat] (32 KB).
// Each wave: scalar-load packed entry, coalesced 128B gather of h_bf[src],
// conflict-free ds_add_f32 into acc[dst_local]. Then bf16 coalesced emit.
__global__ __launch_bounds__(256) void k_bagg(const ushort_t* __restrict__ h_bf,
                                              const int* __restrict__ bucketArr,
                                              const int* __restrict__ bucketCnt,
                                              ushort_t* __restrict__ agg_bf,
                                              int N, int CAP) {
    __shared__ float acc[128 * 64];
    int tid = threadIdx.x;
    int b = blockIdx.x;
    for (int i = tid; i < 8192; i += 256) acc[i] = 0.f;
    __syncthreads();
    int cnt = bucketCnt[b]; if (cnt > CAP) cnt = CAP;
    int base = b * CAP;
    int wv = tid >> 6, lane = tid & 63;
    int i = wv;
    for (; i + 12 < cnt; i += 16) {
        int pk0 = bucketArr[base + i];
        int pk1 = bucketArr[base + i + 4];
        int pk2 = bucketArr[base + i + 8];
        int pk3 = bucketArr[base + i + 12];
        float v0 = bf2f(h_bf[(size_t)(pk0 & 0x1FFFF) * 64 + lane]);
        float v1 = bf2f(h_bf[(size_t)(pk1 & 0x1FFFF) * 64 + lane]);
        float v2 = bf2f(h_bf[(size_t)(pk2 & 0x1FFFF) * 64 + lane]);
        float v3 = bf2f(h_bf[(size_t)(pk3 & 0x1FFFF) * 64 + lane]);
        atomicAdd(&acc[(pk0 >> 17) * 64 + lane], v0);
        atomicAdd(&acc[(pk1 >> 17) * 64 + lane], v1);
        atomicAdd(&acc[(pk2 >> 17) * 64 + lane], v2);
        atomicAdd(&acc[(pk3 >> 17) * 64 + lane], v3);
    }
    for (; i < cnt; i += 4) {
        int pk = bucketArr[base + i];
        atomicAdd(&acc[(pk >> 17) * 64 + lane],
                  bf2f(h_bf[(size_t)(pk & 0x1FFFF) * 64 + lane]));
    }
    __syncthreads();
    int nodeBase = b * 128;
    for (int idx = tid; idx < 8192; idx += 256) {
        int node = nodeBase + (idx >> 6);
        if (node < N) agg_bf[(size_t)node * 64 + (idx & 63)] = f2bf(acc[idx]);
    }
}

// ---------------------------------------------------------------------------
// MFMA tail: h2 = tanh(agg@Wrel + brel + h@Wroot); o = tanh(h2@W2 + b2);
// split + softplus + transposed store. One wave per 16-node tile.
__global__ __launch_bounds__(256) void k_tail(const ushort_t* __restrict__ h_bf,
                                              const ushort_t* __restrict__ agg_bf,
                                              const float* __restrict__ Wrel,
                                              const float* __restrict__ brel,
                                              const float* __restrict__ Wroot,
                                              const float* __restrict__ W2,
                                              const float* __restrict__ b2,
                                              float* __restrict__ out,
                                              int N, int ntiles) {
    __shared__ alignas(16) ushort_t WrelF[8 * 512];   // (kt*4+nt)*512 + lane*8 + j
    __shared__ alignas(16) ushort_t WrootF[8 * 512];
    __shared__ alignas(16) ushort_t W2F[2 * 512];     // kt*512 + lane*8 + j
    __shared__ alignas(16) ushort_t h2T[4][16 * 72];  // per-wave, row stride 72
    __shared__ float brelS[64];
    __shared__ float b2S[16];
    int tid = threadIdx.x;
    for (int i = tid; i < 4096; i += 256) {
        int j = i & 7, lane = (i >> 3) & 63, grp = i >> 9;
        int kt = grp >> 2, nt = grp & 3;
        int k = (kt << 5) + ((lane >> 4) << 3) + j;
        int n = (nt << 4) + (lane & 15);
        WrelF[i]  = f2bf(Wrel[k * 64 + n]);
        WrootF[i] = f2bf(Wroot[k * 64 + n]);
    }
    for (int i = tid; i < 1024; i += 256) {
        int j = i & 7, lane = (i >> 3) & 63, kt = i >> 9;
        int k = (kt << 5) + ((lane >> 4) << 3) + j;
        int n = (lane & 15);
        W2F[i] = f2bf(W2[k * 16 + n]);
    }
    if (tid < 64) brelS[tid] = brel[tid];
    if (tid < 16) b2S[tid] = b2[tid];
    __syncthreads();

    int lane = tid & 63;
    int wv = tid >> 6;
    int lrow = lane & 15;
    int lkg = lane >> 4;
    const bf16x8v* WrelV  = (const bf16x8v*)WrelF;
    const bf16x8v* WrootV = (const bf16x8v*)WrootF;
    const bf16x8v* W2V    = (const bf16x8v*)W2F;
    ushort_t* myT = h2T[wv];

    int tile = blockIdx.x * 4 + wv;
    if (tile >= ntiles) return;
    int rbase = tile * 16;
    int arow = rbase + lrow; if (arow >= N) arow = N - 1;
    const bf16x8v* aggV = (const bf16x8v*)(agg_bf + (size_t)arow * 64);
    const bf16x8v* hV   = (const bf16x8v*)(h_bf + (size_t)arow * 64);
    bf16x8v a0 = aggV[lkg], a1 = aggV[4 + lkg];
    bf16x8v x0 = hV[lkg],   x1 = hV[4 + lkg];

    f32x4 acc[4];
#pragma unroll
    for (int nt = 0; nt < 4; ++nt) { acc[nt] = (f32x4){0.f, 0.f, 0.f, 0.f}; }
#pragma unroll
    for (int nt = 0; nt < 4; ++nt) {
        acc[nt] = __builtin_amdgcn_mfma_f32_16x16x32_bf16(a0, WrelV[(0 * 4 + nt) * 64 + lane], acc[nt], 0, 0, 0);
        acc[nt] = __builtin_amdgcn_mfma_f32_16x16x32_bf16(a1, WrelV[(1 * 4 + nt) * 64 + lane], acc[nt], 0, 0, 0);
        acc[nt] = __builtin_amdgcn_mfma_f32_16x16x32_bf16(x0, WrootV[(0 * 4 + nt) * 64 + lane], acc[nt], 0, 0, 0);
        acc[nt] = __builtin_amdgcn_mfma_f32_16x16x32_bf16(x1, WrootV[(1 * 4 + nt) * 64 + lane], acc[nt], 0, 0, 0);
    }
#pragma unroll
    for (int nt = 0; nt < 4; ++nt) {
        int feat = nt * 16 + lrow;
        float bias = brelS[feat];
#pragma unroll
        for (int r = 0; r < 4; ++r) {
            int noderow = lkg * 4 + r;
            myT[noderow * 72 + feat] = f2bf(tanhf(acc[nt][r] + bias));
        }
    }
    __threadfence_block();
    const bf16x8v* h2V = (const bf16x8v*)myT;
    bf16x8v p0 = h2V[lrow * 9 + lkg];
    bf16x8v p1 = h2V[lrow * 9 + 4 + lkg];
    f32x4 acc2 = (f32x4){0.f, 0.f, 0.f, 0.f};
    acc2 = __builtin_amdgcn_mfma_f32_16x16x32_bf16(p0, W2V[0 * 64 + lane], acc2, 0, 0, 0);
    acc2 = __builtin_amdgcn_mfma_f32_16x16x32_bf16(p1, W2V[1 * 64 + lane], acc2, 0, 0, 0);

    int feat = lrow;
    float bias2 = b2S[feat];
#pragma unroll
    for (int r = 0; r < 4; ++r) {
        int node = rbase + lkg * 4 + r;
        float o = tanhf(acc2[r] + bias2);
        if (feat >= 8) {
            float sp = log1pf(expf(o + SP_BIAS));
            o = fmaxf(sp, 1e-4f);
        }
        if (node < N) out[(size_t)feat * N + node] = o;
    }
}

// ---------------------------------------------------------------------------
extern "C" void kernel_launch(void* const* d_in, const int* in_sizes, int n_in,
                              void* d_out, int out_size, void* d_ws, size_t ws_size,
                              hipStream_t stream) {
    const float* x    = (const float*)d_in[0];
    const int*   ei   = (const int*)d_in[1];
    const float* W1   = (const float*)d_in[2];
    const float* b1   = (const float*)d_in[3];
    const float* Wrel = (const float*)d_in[4];
    const float* brel = (const float*)d_in[5];
    const float* Wroot= (const float*)d_in[6];
    const float* W2   = (const float*)d_in[7];
    const float* b2   = (const float*)d_in[8];

    int N = in_sizes[0] / 27;
    int E = in_sizes[1] / 2;

    int B = (N + 127) / 128;                       // buckets of 128 dsts
    int CAP = ((E + B - 1) / B) * 5 / 4 + 64;      // per-bucket capacity

    ushort_t* h_bf      = (ushort_t*)d_ws;                  // N*64 bf16
    ushort_t* agg_bf    = h_bf + (size_t)N * 64;            // N*64 bf16
    int*      bucketArr = (int*)(agg_bf + (size_t)N * 64);  // B*CAP int
    int*      bucketCnt = bucketArr + (size_t)B * CAP;      // B int
    int*      is32      = bucketCnt + B;                    // 1 int

    int ntiles16 = (N + 15) / 16;

    hipMemsetAsync(bucketCnt, 0, (size_t)(B + 1) * sizeof(int), stream);
    int ncheck = 2 * E < 65536 ? 2 * E : 65536;
    k_detect<<<8, 256, 0, stream>>>(ei, ncheck, is32);
    k_lin1<<<(N + 3) / 4, 256, 0, stream>>>(x, W1, b1, h_bf, N);
    k_bin<<<(E + 4095) / 4096, 256, 0, stream>>>(ei, is32, bucketCnt, bucketArr, E, B, CAP);
    k_bagg<<<B, 256, 0, stream>>>(h_bf, bucketArr, bucketCnt, agg_bf, N, CAP);
    k_tail<<<(ntiles16 + 3) / 4, 256, 0, stream>>>(h_bf, agg_bf, Wrel, brel, Wroot,
                                                   W2, b2, (float*)d_out, N, ntiles16);
}

// Round 5
// 325.971 us; speedup vs baseline: 2.4181x; 2.4181x over previous
//
#include <hip/hip_runtime.h>
#include <hip/hip_bf16.h>
#include <math.h>

typedef unsigned short ushort_t;
typedef float f32x4 __attribute__((ext_vector_type(4)));
typedef short bf16x8v __attribute__((ext_vector_type(8)));

static constexpr float SP_BIAS = 0.5413248546129181f; // log(expm1(1.0))

__device__ __forceinline__ ushort_t f2bf(float f) {
    union { float f; unsigned u; } v; v.f = f;
    unsigned r = v.u + 0x7FFFu + ((v.u >> 16) & 1u);   // RNE
    return (ushort_t)(r >> 16);
}
__device__ __forceinline__ float bf2f(ushort_t u) {
    union { unsigned u; float f; } v; v.u = ((unsigned)u) << 16;
    return v.f;
}

// ---------------------------------------------------------------------------
// Detect int32 vs int64 edge_index layout. is32 pre-zeroed; set 1 if any odd
// int32 word nonzero (-> genuine int32 pairs, not int64 low-words).
__global__ void k_detect(const int* __restrict__ ei32, int n_check,
                         int* __restrict__ is32) {
    int idx = blockIdx.x * 256 + threadIdx.x;
    int found = 0;
    for (int i = idx; i < n_check; i += 2048) {
        if (ei32[2 * i + 1] != 0) { found = 1; break; }
    }
    if (found) atomicOr(is32, 1);
}

// ---------------------------------------------------------------------------
// h_bf = bf16(x @ W1 + b1); 4 nodes/block, thread t of wave g -> feature t.
__global__ __launch_bounds__(256) void k_lin1(const float* __restrict__ x,
                                              const float* __restrict__ W1,
                                              const float* __restrict__ b1,
                                              ushort_t* __restrict__ h_bf, int N) {
    __shared__ float Ws[27 * 64];
    __shared__ float bs[64];
    __shared__ float xs[4 * 27];
    int tid = threadIdx.x;
    for (int i = tid; i < 27 * 64; i += 256) Ws[i] = W1[i];
    if (tid < 64) bs[tid] = b1[tid];
    int base = blockIdx.x * 4;
    if (tid < 108) {
        int gidx = base * 27 + tid;
        xs[tid] = (gidx < N * 27) ? x[gidx] : 0.f;
    }
    __syncthreads();
    int g = tid >> 6, t = tid & 63;
    int node = base + g;
    if (node < N) {
        float acc = bs[t];
        const float* xr = &xs[g * 27];
#pragma unroll
        for (int k = 0; k < 27; ++k) acc = fmaf(xr[k], Ws[k * 64 + t], acc);
        h_bf[(size_t)node * 64 + t] = f2bf(acc);
    }
}

// ---------------------------------------------------------------------------
// Fused hist + 8-way binning by dst&7. Per block (2048 edges): LDS hist of 8,
// reserve contiguous runs in bucketArr via one global atomic per bucket, then
// burst-write packed ((dst>>3)<<17)|src entries. Also deg[dst]++ per edge.
__global__ __launch_bounds__(256) void k_bin(const int* __restrict__ ei,
                                             const int* __restrict__ is32,
                                             int* __restrict__ deg,
                                             int* __restrict__ bucketCnt8,
                                             int* __restrict__ bucketArr,
                                             int E, int CAP8) {
    __shared__ int hist[8];
    __shared__ int cur[8];
    int tid = threadIdx.x;
    if (tid < 8) hist[tid] = 0;
    __syncthreads();
    int e0 = blockIdx.x * 2048;
    int mode32 = *is32;
#pragma unroll
    for (int k = 0; k < 8; ++k) {
        int e = e0 + k * 256 + tid;
        if (e < E) {
            int dst = mode32 ? ei[E + e] : ((const int2*)ei)[E + e].x;
            atomicAdd(&deg[dst], 1);
            atomicAdd(&hist[dst & 7], 1);
        }
    }
    __syncthreads();
    if (tid < 8) {
        int c = hist[tid];
        if (c > 0) cur[tid] = tid * CAP8 + atomicAdd(&bucketCnt8[tid], c);
    }
    __syncthreads();
#pragma unroll
    for (int k = 0; k < 8; ++k) {
        int e = e0 + k * 256 + tid;
        if (e < E) {
            int src, dst;
            if (mode32) { src = ei[e]; dst = ei[E + e]; }
            else { src = ((const int2*)ei)[e].x; dst = ((const int2*)ei)[E + e].x; }
            int b = dst & 7;
            int slot = atomicAdd(&cur[b], 1);
            if (slot < (b + 1) * CAP8)
                bucketArr[slot] = ((dst >> 3) << 17) | src;
        }
    }
}

// ---------------------------------------------------------------------------
#define SCAN_TILE 1024
__global__ __launch_bounds__(256) void k_scan1(const int* __restrict__ deg,
                                               int* __restrict__ cursor,
                                               int* __restrict__ blockSums,
                                               int N) {
    __shared__ int sdata[256];
    int tid = threadIdx.x;
    int base = blockIdx.x * SCAN_TILE + tid * 4;
    int v[4];
#pragma unroll
    for (int j = 0; j < 4; ++j) {
        int idx = base + j;
        v[j] = (idx < N) ? deg[idx] : 0;
    }
    int tsum = v[0] + v[1] + v[2] + v[3];
    sdata[tid] = tsum;
    __syncthreads();
    for (int off = 1; off < 256; off <<= 1) {
        int add = (tid >= off) ? sdata[tid - off] : 0;
        __syncthreads();
        sdata[tid] += add;
        __syncthreads();
    }
    int run = sdata[tid] - tsum;
#pragma unroll
    for (int j = 0; j < 4; ++j) {
        int idx = base + j;
        if (idx < N) cursor[idx] = run;
        run += v[j];
    }
    if (tid == 255) blockSums[blockIdx.x] = sdata[255];
}

__global__ __launch_bounds__(256) void k_scan2(int* __restrict__ blockSums,
                                               int numTiles) {
    __shared__ int sdata[256];
    int tid = threadIdx.x;
    int v = (tid < numTiles) ? blockSums[tid] : 0;
    sdata[tid] = v;
    __syncthreads();
    for (int off = 1; off < 256; off <<= 1) {
        int add = (tid >= off) ? sdata[tid - off] : 0;
        __syncthreads();
        sdata[tid] += add;
        __syncthreads();
    }
    if (tid < numTiles) blockSums[tid] = sdata[tid] - v;
}

__global__ __launch_bounds__(256) void k_scan3(int* __restrict__ cursor,
                                               const int* __restrict__ blockSums,
                                               int N) {
    int off = blockSums[blockIdx.x];
    int base = blockIdx.x * SCAN_TILE + threadIdx.x * 4;
#pragma unroll
    for (int j = 0; j < 4; ++j) {
        int idx = base + j;
        if (idx < N) cursor[idx] += off;
    }
}

// ---------------------------------------------------------------------------
// XCD-pinned CSR fill: block b handles residue r=b&7, chunk b>>3 of bucket r.
// Sequential packed reads; scattered src_sorted stores confined to dst%8==r
// rows -> dirty lines owned by one XCD -> minimal write-back.
__global__ __launch_bounds__(256) void k_fill2(const int* __restrict__ bucketArr,
                                               const int* __restrict__ bucketCnt8,
                                               int* __restrict__ cursor,
                                               int* __restrict__ src_sorted,
                                               int CAP8, int nchunks) {
    int r = blockIdx.x & 7;
    int chunk = blockIdx.x >> 3;
    int cnt = bucketCnt8[r]; if (cnt > CAP8) cnt = CAP8;
    int per = (cnt + nchunks - 1) / nchunks;
    int s = chunk * per;
    int e = s + per; if (e > cnt) e = cnt;
    const int* arr = bucketArr + (size_t)r * CAP8;
    for (int i = s + threadIdx.x; i < e; i += 256) {
        int pk = arr[i];
        int src = pk & 0x1FFFF;
        int dst = ((pk >> 17) << 3) | r;
        int pos = atomicAdd(&cursor[dst], 1);
        src_sorted[pos] = src;
    }
}

// ---------------------------------------------------------------------------
// agg_bf[n] = bf16( sum_{s in row n} h_bf[s] ). One wave per node, lane t =
// feature t. No LDS, no barriers; 8-deep unrolled independent loads.
__global__ __launch_bounds__(256) void k_agg(const ushort_t* __restrict__ h_bf,
                                             const int* __restrict__ src_sorted,
                                             const int* __restrict__ rowend,
                                             const int* __restrict__ deg,
                                             ushort_t* __restrict__ agg_bf, int N) {
    int w = (blockIdx.x * 256 + threadIdx.x) >> 6;
    int t = threadIdx.x & 63;
    if (w >= N) return;
    int end = rowend[w];
    int i = end - deg[w];
    float a = 0.f;
    for (; i + 8 <= end; i += 8) {
        int s0 = src_sorted[i],     s1 = src_sorted[i + 1];
        int s2 = src_sorted[i + 2], s3 = src_sorted[i + 3];
        int s4 = src_sorted[i + 4], s5 = src_sorted[i + 5];
        int s6 = src_sorted[i + 6], s7 = src_sorted[i + 7];
        float v0 = bf2f(h_bf[(size_t)s0 * 64 + t]);
        float v1 = bf2f(h_bf[(size_t)s1 * 64 + t]);
        float v2 = bf2f(h_bf[(size_t)s2 * 64 + t]);
        float v3 = bf2f(h_bf[(size_t)s3 * 64 + t]);
        float v4 = bf2f(h_bf[(size_t)s4 * 64 + t]);
        float v5 = bf2f(h_bf[(size_t)s5 * 64 + t]);
        float v6 = bf2f(h_bf[(size_t)s6 * 64 + t]);
        float v7 = bf2f(h_bf[(size_t)s7 * 64 + t]);
        a += ((v0 + v1) + (v2 + v3)) + ((v4 + v5) + (v6 + v7));
    }
    for (; i < end; ++i) a += bf2f(h_bf[(size_t)src_sorted[i] * 64 + t]);
    agg_bf[(size_t)w * 64 + t] = f2bf(a);
}

// ---------------------------------------------------------------------------
// MFMA tail: h2 = tanh(agg@Wrel + brel + h@Wroot); o = tanh(h2@W2 + b2);
// split + softplus + transposed store. One wave per 16-node tile.
__global__ __launch_bounds__(256) void k_tail(const ushort_t* __restrict__ h_bf,
                                              const ushort_t* __restrict__ agg_bf,
                                              const float* __restrict__ Wrel,
                                              const float* __restrict__ brel,
                                              const float* __restrict__ Wroot,
                                              const float* __restrict__ W2,
                                              const float* __restrict__ b2,
                                              float* __restrict__ out,
                                              int N, int ntiles) {
    __shared__ alignas(16) ushort_t WrelF[8 * 512];   // (kt*4+nt)*512 + lane*8 + j
    __shared__ alignas(16) ushort_t WrootF[8 * 512];
    __shared__ alignas(16) ushort_t W2F[2 * 512];     // kt*512 + lane*8 + j
    __shared__ alignas(16) ushort_t h2T[4][16 * 72];  // per-wave, row stride 72
    __shared__ float brelS[64];
    __shared__ float b2S[16];
    int tid = threadIdx.x;
    for (int i = tid; i < 4096; i += 256) {
        int j = i & 7, lane = (i >> 3) & 63, grp = i >> 9;
        int kt = grp >> 2, nt = grp & 3;
        int k = (kt << 5) + ((lane >> 4) << 3) + j;
        int n = (nt << 4) + (lane & 15);
        WrelF[i]  = f2bf(Wrel[k * 64 + n]);
        WrootF[i] = f2bf(Wroot[k * 64 + n]);
    }
    for (int i = tid; i < 1024; i += 256) {
        int j = i & 7, lane = (i >> 3) & 63, kt = i >> 9;
        int k = (kt << 5) + ((lane >> 4) << 3) + j;
        int n = (lane & 15);
        W2F[i] = f2bf(W2[k * 16 + n]);
    }
    if (tid < 64) brelS[tid] = brel[tid];
    if (tid < 16) b2S[tid] = b2[tid];
    __syncthreads();

    int lane = tid & 63;
    int wv = tid >> 6;
    int lrow = lane & 15;
    int lkg = lane >> 4;
    const bf16x8v* WrelV  = (const bf16x8v*)WrelF;
    const bf16x8v* WrootV = (const bf16x8v*)WrootF;
    const bf16x8v* W2V    = (const bf16x8v*)W2F;
    ushort_t* myT = h2T[wv];

    int tile = blockIdx.x * 4 + wv;
    if (tile >= ntiles) return;
    int rbase = tile * 16;
    int arow = rbase + lrow; if (arow >= N) arow = N - 1;
    const bf16x8v* aggV = (const bf16x8v*)(agg_bf + (size_t)arow * 64);
    const bf16x8v* hV   = (const bf16x8v*)(h_bf + (size_t)arow * 64);
    bf16x8v a0 = aggV[lkg], a1 = aggV[4 + lkg];
    bf16x8v x0 = hV[lkg],   x1 = hV[4 + lkg];

    f32x4 acc[4];
#pragma unroll
    for (int nt = 0; nt < 4; ++nt) { acc[nt] = (f32x4){0.f, 0.f, 0.f, 0.f}; }
#pragma unroll
    for (int nt = 0; nt < 4; ++nt) {
        acc[nt] = __builtin_amdgcn_mfma_f32_16x16x32_bf16(a0, WrelV[(0 * 4 + nt) * 64 + lane], acc[nt], 0, 0, 0);
        acc[nt] = __builtin_amdgcn_mfma_f32_16x16x32_bf16(a1, WrelV[(1 * 4 + nt) * 64 + lane], acc[nt], 0, 0, 0);
        acc[nt] = __builtin_amdgcn_mfma_f32_16x16x32_bf16(x0, WrootV[(0 * 4 + nt) * 64 + lane], acc[nt], 0, 0, 0);
        acc[nt] = __builtin_amdgcn_mfma_f32_16x16x32_bf16(x1, WrootV[(1 * 4 + nt) * 64 + lane], acc[nt], 0, 0, 0);
    }
#pragma unroll
    for (int nt = 0; nt < 4; ++nt) {
        int feat = nt * 16 + lrow;
        float bias = brelS[feat];
#pragma unroll
        for (int r = 0; r < 4; ++r) {
            int noderow = lkg * 4 + r;
            myT[noderow * 72 + feat] = f2bf(tanhf(acc[nt][r] + bias));
        }
    }
    __threadfence_block();
    const bf16x8v* h2V = (const bf16x8v*)myT;
    bf16x8v p0 = h2V[lrow * 9 + lkg];
    bf16x8v p1 = h2V[lrow * 9 + 4 + lkg];
    f32x4 acc2 = (f32x4){0.f, 0.f, 0.f, 0.f};
    acc2 = __builtin_amdgcn_mfma_f32_16x16x32_bf16(p0, W2V[0 * 64 + lane], acc2, 0, 0, 0);
    acc2 = __builtin_amdgcn_mfma_f32_16x16x32_bf16(p1, W2V[1 * 64 + lane], acc2, 0, 0, 0);

    int feat = lrow;
    float bias2 = b2S[feat];
#pragma unroll
    for (int r = 0; r < 4; ++r) {
        int node = rbase + lkg * 4 + r;
        float o = tanhf(acc2[r] + bias2);
        if (feat >= 8) {
            float sp = log1pf(expf(o + SP_BIAS));
            o = fmaxf(sp, 1e-4f);
        }
        if (node < N) out[(size_t)feat * N + node] = o;
    }
}

// ---------------------------------------------------------------------------
extern "C" void kernel_launch(void* const* d_in, const int* in_sizes, int n_in,
                              void* d_out, int out_size, void* d_ws, size_t ws_size,
                              hipStream_t stream) {
    const float* x    = (const float*)d_in[0];
    const int*   ei   = (const int*)d_in[1];
    const float* W1   = (const float*)d_in[2];
    const float* b1   = (const float*)d_in[3];
    const float* Wrel = (const float*)d_in[4];
    const float* brel = (const float*)d_in[5];
    const float* Wroot= (const float*)d_in[6];
    const float* W2   = (const float*)d_in[7];
    const float* b2   = (const float*)d_in[8];

    int N = in_sizes[0] / 27;
    int E = in_sizes[1] / 2;

    int CAP8 = E / 8 + E / 64 + 1024;   // per-residue bucket capacity

    ushort_t* h_bf       = (ushort_t*)d_ws;                  // N*64 bf16
    ushort_t* agg_bf     = h_bf + (size_t)N * 64;            // N*64 bf16
    int*      src_sorted = (int*)(agg_bf + (size_t)N * 64);  // E int
    int*      bucketArr  = src_sorted + E;                   // 8*CAP8 int
    int*      cursor     = bucketArr + (size_t)8 * CAP8;     // N int
    int*      deg        = cursor + N;                       // N int (zeroed)
    int*      blockSums  = deg + N;                          // 256 int (zeroed)
    int*      bucketCnt8 = blockSums + 256;                  // 8 int (zeroed)
    int*      is32       = bucketCnt8 + 8;                   // 1 int (zeroed)

    int numTiles = (N + SCAN_TILE - 1) / SCAN_TILE;
    int ntiles16 = (N + 15) / 16;

    hipMemsetAsync(deg, 0, (size_t)(N + 256 + 8 + 1) * sizeof(int), stream);
    int ncheck = 2 * E < 65536 ? 2 * E : 65536;
    k_detect<<<8, 256, 0, stream>>>(ei, ncheck, is32);
    k_lin1<<<(N + 3) / 4, 256, 0, stream>>>(x, W1, b1, h_bf, N);
    k_bin<<<(E + 2047) / 2048, 256, 0, stream>>>(ei, is32, deg, bucketCnt8,
                                                 bucketArr, E, CAP8);
    k_scan1<<<numTiles, 256, 0, stream>>>(deg, cursor, blockSums, N);
    k_scan2<<<1, 256, 0, stream>>>(blockSums, numTiles);
    k_scan3<<<numTiles, 256, 0, stream>>>(cursor, blockSums, N);
    k_fill2<<<2048, 256, 0, stream>>>(bucketArr, bucketCnt8, cursor, src_sorted,
                                      CAP8, 256);
    k_agg<<<(N + 3) / 4, 256, 0, stream>>>(h_bf, src_sorted, cursor, deg, agg_bf, N);
    k_tail<<<(ntiles16 + 3) / 4, 256, 0, stream>>>(h_bf, agg_bf, Wrel, brel, Wroot,
                                                   W2, b2, (float*)d_out, N, ntiles16);
}

// Round 6
// 181.597 us; speedup vs baseline: 4.3406x; 1.7950x over previous
//
#include <hip/hip_runtime.h>
#include <hip/hip_bf16.h>
#include <math.h>

typedef unsigned short ushort_t;
typedef float f32x4 __attribute__((ext_vector_type(4)));
typedef short bf16x8v __attribute__((ext_vector_type(8)));

static constexpr float SP_BIAS = 0.5413248546129181f; // log(expm1(1.0))
#define LB   512     // nodes per bucket (9 bits local index)
#define LCAP 12288   // max entries per bucket (mean 8163, +45 sigma)
#define MAXB 256     // max buckets -> N <= 131072 (17-bit src pack)

__device__ __forceinline__ ushort_t f2bf(float f) {
    union { float f; unsigned u; } v; v.f = f;
    unsigned r = v.u + 0x7FFFu + ((v.u >> 16) & 1u);   // RNE
    return (ushort_t)(r >> 16);
}
__device__ __forceinline__ float bf2f(ushort_t u) {
    union { unsigned u; float f; } v; v.u = ((unsigned)u) << 16;
    return v.f;
}

// ---------------------------------------------------------------------------
// Detect int32 vs int64 edge_index layout. is32 pre-zeroed; set 1 if any odd
// int32 word nonzero (-> genuine int32 pairs, not int64 low-words).
__global__ void k_detect(const int* __restrict__ ei32, int n_check,
                         int* __restrict__ is32) {
    int idx = blockIdx.x * 256 + threadIdx.x;
    int found = 0;
    for (int i = idx; i < n_check; i += 2048) {
        if (ei32[2 * i + 1] != 0) { found = 1; break; }
    }
    if (found) atomicOr(is32, 1);
}

// ---------------------------------------------------------------------------
// h_bf = bf16(x @ W1 + b1); 4 nodes/block, thread t of wave g -> feature t.
__global__ __launch_bounds__(256) void k_lin1(const float* __restrict__ x,
                                              const float* __restrict__ W1,
                                              const float* __restrict__ b1,
                                              ushort_t* __restrict__ h_bf, int N) {
    __shared__ float Ws[27 * 64];
    __shared__ float bs[64];
    __shared__ float xs[4 * 27];
    int tid = threadIdx.x;
    for (int i = tid; i < 27 * 64; i += 256) Ws[i] = W1[i];
    if (tid < 64) bs[tid] = b1[tid];
    int base = blockIdx.x * 4;
    if (tid < 108) {
        int gidx = base * 27 + tid;
        xs[tid] = (gidx < N * 27) ? x[gidx] : 0.f;
    }
    __syncthreads();
    int g = tid >> 6, t = tid & 63;
    int node = base + g;
    if (node < N) {
        float acc = bs[t];
        const float* xr = &xs[g * 27];
#pragma unroll
        for (int k = 0; k < 27; ++k) acc = fmaf(xr[k], Ws[k * 64 + t], acc);
        h_bf[(size_t)node * 64 + t] = f2bf(acc);
    }
}

// ---------------------------------------------------------------------------
// Bin edges into NB buckets of 512 consecutive dsts. Per block (4096 edges):
// LDS hist -> reserve contiguous runs (1 global atomic per nonempty bucket)
// -> burst-write packed ((dst&511)<<17)|src entries.
__global__ __launch_bounds__(256) void k_bin(const int* __restrict__ ei,
                                             const int* __restrict__ is32,
                                             int* __restrict__ bucketCnt,
                                             int* __restrict__ bucketArr,
                                             int E, int NB, int CAP) {
    __shared__ int hist[MAXB];
    __shared__ int cur[MAXB];
    int tid = threadIdx.x;
    for (int i = tid; i < NB; i += 256) hist[i] = 0;
    __syncthreads();
    int e0 = blockIdx.x * 4096;
    int mode32 = *is32;
#pragma unroll
    for (int k = 0; k < 16; ++k) {
        int e = e0 + k * 256 + tid;
        if (e < E) {
            int dst = mode32 ? ei[E + e] : ((const int2*)ei)[E + e].x;
            atomicAdd(&hist[dst >> 9], 1);
        }
    }
    __syncthreads();
    for (int b = tid; b < NB; b += 256) {
        int c = hist[b];
        if (c > 0) cur[b] = b * CAP + atomicAdd(&bucketCnt[b], c);
    }
    __syncthreads();
#pragma unroll
    for (int k = 0; k < 16; ++k) {
        int e = e0 + k * 256 + tid;
        if (e < E) {
            int src, dst;
            if (mode32) { src = ei[e]; dst = ei[E + e]; }
            else { src = ((const int2*)ei)[e].x; dst = ((const int2*)ei)[E + e].x; }
            int b = dst >> 9;
            int slot = atomicAdd(&cur[b], 1);
            if (slot < (b + 1) * CAP)
                bucketArr[slot] = ((dst & 511) << 17) | src;
        }
    }
}

// ---------------------------------------------------------------------------
// Exclusive scan of bucketCnt (NB <= 256) -> bucketBase. One block.
__global__ __launch_bounds__(256) void k_bscan(const int* __restrict__ bucketCnt,
                                               int* __restrict__ bucketBase,
                                               int NB) {
    __shared__ int sdata[256];
    int tid = threadIdx.x;
    int v = (tid < NB) ? bucketCnt[tid] : 0;
    sdata[tid] = v;
    __syncthreads();
    for (int off = 1; off < 256; off <<= 1) {
        int add = (tid >= off) ? sdata[tid - off] : 0;
        __syncthreads();
        sdata[tid] += add;
        __syncthreads();
    }
    if (tid < NB) bucketBase[tid] = sdata[tid] - v;
}

// ---------------------------------------------------------------------------
// Per-bucket LDS counting sort -> CSR segment. One block per bucket.
// All scattered stores land in LDS; global writes fully coalesced.
__global__ __launch_bounds__(256) void k_local(const int* __restrict__ bucketArr,
                                               const int* __restrict__ bucketCnt,
                                               const int* __restrict__ bucketBase,
                                               int* __restrict__ src_sorted,
                                               int* __restrict__ rowend,
                                               int* __restrict__ deg_g,
                                               int N, int CAP) {
    __shared__ int hist[LB];
    __shared__ int incl[LB];
    __shared__ int cursor[LB];
    __shared__ int sdata[256];
    __shared__ int sorted[LCAP];
    int b = blockIdx.x, tid = threadIdx.x;
    for (int i = tid; i < LB; i += 256) hist[i] = 0;
    __syncthreads();
    int cnt = bucketCnt[b];
    if (cnt > CAP) cnt = CAP;
    if (cnt > LCAP) cnt = LCAP;
    const int* arr = bucketArr + (size_t)b * CAP;
    for (int i = tid; i < cnt; i += 256) atomicAdd(&hist[arr[i] >> 17], 1);
    __syncthreads();
    // scan 512 counters with 256 threads (pairs + Hillis-Steele)
    int v0 = hist[2 * tid], v1 = hist[2 * tid + 1];
    int psum = v0 + v1;
    sdata[tid] = psum;
    __syncthreads();
    for (int off = 1; off < 256; off <<= 1) {
        int add = (tid >= off) ? sdata[tid - off] : 0;
        __syncthreads();
        sdata[tid] += add;
        __syncthreads();
    }
    int pexcl = sdata[tid] - psum;
    incl[2 * tid] = pexcl + v0;
    incl[2 * tid + 1] = pexcl + v0 + v1;
    cursor[2 * tid] = pexcl;
    cursor[2 * tid + 1] = pexcl + v0;
    __syncthreads();
    for (int i = tid; i < cnt; i += 256) {
        int pk = arr[i];                 // L2 hit (2nd read)
        int pos = atomicAdd(&cursor[pk >> 17], 1);
        sorted[pos] = pk & 0x1FFFF;
    }
    __syncthreads();
    int base = bucketBase[b];
    for (int i = tid; i < cnt; i += 256) src_sorted[base + i] = sorted[i];
    int n0 = b * LB;
    for (int ln = tid; ln < LB; ln += 256) {
        int node = n0 + ln;
        if (node < N) {
            rowend[node] = base + incl[ln];
            deg_g[node] = hist[ln];
        }
    }
}

// ---------------------------------------------------------------------------
// agg_bf[n] = bf16( sum_{s in row n} h_bf[s] ). One wave per node, lane t =
// feature t. No LDS, no barriers; 8-deep unrolled independent loads.
__global__ __launch_bounds__(256) void k_agg(const ushort_t* __restrict__ h_bf,
                                             const int* __restrict__ src_sorted,
                                             const int* __restrict__ rowend,
                                             const int* __restrict__ deg,
                                             ushort_t* __restrict__ agg_bf, int N) {
    int w = (blockIdx.x * 256 + threadIdx.x) >> 6;
    int t = threadIdx.x & 63;
    if (w >= N) return;
    int end = rowend[w];
    int i = end - deg[w];
    float a = 0.f;
    for (; i + 8 <= end; i += 8) {
        int s0 = src_sorted[i],     s1 = src_sorted[i + 1];
        int s2 = src_sorted[i + 2], s3 = src_sorted[i + 3];
        int s4 = src_sorted[i + 4], s5 = src_sorted[i + 5];
        int s6 = src_sorted[i + 6], s7 = src_sorted[i + 7];
        float v0 = bf2f(h_bf[(size_t)s0 * 64 + t]);
        float v1 = bf2f(h_bf[(size_t)s1 * 64 + t]);
        float v2 = bf2f(h_bf[(size_t)s2 * 64 + t]);
        float v3 = bf2f(h_bf[(size_t)s3 * 64 + t]);
        float v4 = bf2f(h_bf[(size_t)s4 * 64 + t]);
        float v5 = bf2f(h_bf[(size_t)s5 * 64 + t]);
        float v6 = bf2f(h_bf[(size_t)s6 * 64 + t]);
        float v7 = bf2f(h_bf[(size_t)s7 * 64 + t]);
        a += ((v0 + v1) + (v2 + v3)) + ((v4 + v5) + (v6 + v7));
    }
    for (; i < end; ++i) a += bf2f(h_bf[(size_t)src_sorted[i] * 64 + t]);
    agg_bf[(size_t)w * 64 + t] = f2bf(a);
}

// ---------------------------------------------------------------------------
// MFMA tail: h2 = tanh(agg@Wrel + brel + h@Wroot); o = tanh(h2@W2 + b2);
// split + softplus + transposed store. One wave per 16-node tile.
__global__ __launch_bounds__(256) void k_tail(const ushort_t* __restrict__ h_bf,
                                              const ushort_t* __restrict__ agg_bf,
                                              const float* __restrict__ Wrel,
                                              const float* __restrict__ brel,
                                              const float* __restrict__ Wroot,
                                              const float* __restrict__ W2,
                                              const float* __restrict__ b2,
                                              float* __restrict__ out,
                                              int N, int ntiles) {
    __shared__ alignas(16) ushort_t WrelF[8 * 512];   // (kt*4+nt)*512 + lane*8 + j
    __shared__ alignas(16) ushort_t WrootF[8 * 512];
    __shared__ alignas(16) ushort_t W2F[2 * 512];     // kt*512 + lane*8 + j
    __shared__ alignas(16) ushort_t h2T[4][16 * 72];  // per-wave, row stride 72
    __shared__ float brelS[64];
    __shared__ float b2S[16];
    int tid = threadIdx.x;
    for (int i = tid; i < 4096; i += 256) {
        int j = i & 7, lane = (i >> 3) & 63, grp = i >> 9;
        int kt = grp >> 2, nt = grp & 3;
        int k = (kt << 5) + ((lane >> 4) << 3) + j;
        int n = (nt << 4) + (lane & 15);
        WrelF[i]  = f2bf(Wrel[k * 64 + n]);
        WrootF[i] = f2bf(Wroot[k * 64 + n]);
    }
    for (int i = tid; i < 1024; i += 256) {
        int j = i & 7, lane = (i >> 3) & 63, kt = i >> 9;
        int k = (kt << 5) + ((lane >> 4) << 3) + j;
        int n = (lane & 15);
        W2F[i] = f2bf(W2[k * 16 + n]);
    }
    if (tid < 64) brelS[tid] = brel[tid];
    if (tid < 16) b2S[tid] = b2[tid];
    __syncthreads();

    int lane = tid & 63;
    int wv = tid >> 6;
    int lrow = lane & 15;
    int lkg = lane >> 4;
    const bf16x8v* WrelV  = (const bf16x8v*)WrelF;
    const bf16x8v* WrootV = (const bf16x8v*)WrootF;
    const bf16x8v* W2V    = (const bf16x8v*)W2F;
    ushort_t* myT = h2T[wv];

    int tile = blockIdx.x * 4 + wv;
    if (tile >= ntiles) return;
    int rbase = tile * 16;
    int arow = rbase + lrow; if (arow >= N) arow = N - 1;
    const bf16x8v* aggV = (const bf16x8v*)(agg_bf + (size_t)arow * 64);
    const bf16x8v* hV   = (const bf16x8v*)(h_bf + (size_t)arow * 64);
    bf16x8v a0 = aggV[lkg], a1 = aggV[4 + lkg];
    bf16x8v x0 = hV[lkg],   x1 = hV[4 + lkg];

    f32x4 acc[4];
#pragma unroll
    for (int nt = 0; nt < 4; ++nt) { acc[nt] = (f32x4){0.f, 0.f, 0.f, 0.f}; }
#pragma unroll
    for (int nt = 0; nt < 4; ++nt) {
        acc[nt] = __builtin_amdgcn_mfma_f32_16x16x32_bf16(a0, WrelV[(0 * 4 + nt) * 64 + lane], acc[nt], 0, 0, 0);
        acc[nt] = __builtin_amdgcn_mfma_f32_16x16x32_bf16(a1, WrelV[(1 * 4 + nt) * 64 + lane], acc[nt], 0, 0, 0);
        acc[nt] = __builtin_amdgcn_mfma_f32_16x16x32_bf16(x0, WrootV[(0 * 4 + nt) * 64 + lane], acc[nt], 0, 0, 0);
        acc[nt] = __builtin_amdgcn_mfma_f32_16x16x32_bf16(x1, WrootV[(1 * 4 + nt) * 64 + lane], acc[nt], 0, 0, 0);
    }
#pragma unroll
    for (int nt = 0; nt < 4; ++nt) {
        int feat = nt * 16 + lrow;
        float bias = brelS[feat];
#pragma unroll
        for (int r = 0; r < 4; ++r) {
            int noderow = lkg * 4 + r;
            myT[noderow * 72 + feat] = f2bf(tanhf(acc[nt][r] + bias));
        }
    }
    __threadfence_block();
    const bf16x8v* h2V = (const bf16x8v*)myT;
    bf16x8v p0 = h2V[lrow * 9 + lkg];
    bf16x8v p1 = h2V[lrow * 9 + 4 + lkg];
    f32x4 acc2 = (f32x4){0.f, 0.f, 0.f, 0.f};
    acc2 = __builtin_amdgcn_mfma_f32_16x16x32_bf16(p0, W2V[0 * 64 + lane], acc2, 0, 0, 0);
    acc2 = __builtin_amdgcn_mfma_f32_16x16x32_bf16(p1, W2V[1 * 64 + lane], acc2, 0, 0, 0);

    int feat = lrow;
    float bias2 = b2S[feat];
#pragma unroll
    for (int r = 0; r < 4; ++r) {
        int node = rbase + lkg * 4 + r;
        float o = tanhf(acc2[r] + bias2);
        if (feat >= 8) {
            float sp = log1pf(expf(o + SP_BIAS));
            o = fmaxf(sp, 1e-4f);
        }
        if (node < N) out[(size_t)feat * N + node] = o;
    }
}

// ---------------------------------------------------------------------------
extern "C" void kernel_launch(void* const* d_in, const int* in_sizes, int n_in,
                              void* d_out, int out_size, void* d_ws, size_t ws_size,
                              hipStream_t stream) {
    const float* x    = (const float*)d_in[0];
    const int*   ei   = (const int*)d_in[1];
    const float* W1   = (const float*)d_in[2];
    const float* b1   = (const float*)d_in[3];
    const float* Wrel = (const float*)d_in[4];
    const float* brel = (const float*)d_in[5];
    const float* Wroot= (const float*)d_in[6];
    const float* W2   = (const float*)d_in[7];
    const float* b2   = (const float*)d_in[8];

    int N = in_sizes[0] / 27;
    int E = in_sizes[1] / 2;

    int NB = (N + LB - 1) / LB;     // buckets of 512 dsts
    int CAP = LCAP;                 // per-bucket capacity (mean + 45 sigma)

    ushort_t* h_bf       = (ushort_t*)d_ws;                  // N*64 bf16
    ushort_t* agg_bf     = h_bf + (size_t)N * 64;            // N*64 bf16
    int*      src_sorted = (int*)(agg_bf + (size_t)N * 64);  // E int
    int*      bucketArr  = src_sorted + E;                   // NB*CAP int
    int*      bucketCnt  = bucketArr + (size_t)NB * CAP;     // NB int (zeroed)
    int*      is32       = bucketCnt + NB;                   // 1 int (zeroed)
    int*      bucketBase = is32 + 1;                         // NB int
    int*      deg        = bucketBase + NB;                  // N int
    int*      rowend     = deg + N;                          // N int

    int ntiles16 = (N + 15) / 16;

    hipMemsetAsync(bucketCnt, 0, (size_t)(NB + 1) * sizeof(int), stream);
    int ncheck = 2 * E < 65536 ? 2 * E : 65536;
    k_detect<<<8, 256, 0, stream>>>(ei, ncheck, is32);
    k_lin1<<<(N + 3) / 4, 256, 0, stream>>>(x, W1, b1, h_bf, N);
    k_bin<<<(E + 4095) / 4096, 256, 0, stream>>>(ei, is32, bucketCnt, bucketArr,
                                                 E, NB, CAP);
    k_bscan<<<1, 256, 0, stream>>>(bucketCnt, bucketBase, NB);
    k_local<<<NB, 256, 0, stream>>>(bucketArr, bucketCnt, bucketBase,
                                    src_sorted, rowend, deg, N, CAP);
    k_agg<<<(N + 3) / 4, 256, 0, stream>>>(h_bf, src_sorted, rowend, deg, agg_bf, N);
    k_tail<<<(ntiles16 + 3) / 4, 256, 0, stream>>>(h_bf, agg_bf, Wrel, brel, Wroot,
                                                   W2, b2, (float*)d_out, N, ntiles16);
}

// Round 7
// 159.617 us; speedup vs baseline: 4.9383x; 1.1377x over previous
//
#include <hip/hip_runtime.h>
#include <hip/hip_bf16.h>
#include <math.h>

typedef unsigned short ushort_t;
typedef float f32x4 __attribute__((ext_vector_type(4)));
typedef short bf16x8v __attribute__((ext_vector_type(8)));

static constexpr float SP_BIAS = 0.5413248546129181f; // log(expm1(1.0))
#define LB   512     // nodes per bucket (9-bit local index)
#define LCAP 12288   // max compact entries per bucket (mean 8163)
#define PCAP 16384   // fixed padded stride per bucket (>= LCAP + 512*7)
#define MAXB 256     // max buckets -> N <= 131072 (17-bit src pack)

__device__ __forceinline__ ushort_t f2bf(float f) {
    union { float f; unsigned u; } v; v.f = f;
    unsigned r = v.u + 0x7FFFu + ((v.u >> 16) & 1u);   // RNE
    return (ushort_t)(r >> 16);
}
__device__ __forceinline__ float bf2f(ushort_t u) {
    union { unsigned u; float f; } v; v.u = ((unsigned)u) << 16;
    return v.f;
}
__device__ __forceinline__ float hi2f(unsigned u) {
    union { unsigned u; float f; } v; v.u = u & 0xFFFF0000u;
    return v.f;
}
__device__ __forceinline__ float lo2f(unsigned u) {
    union { unsigned u; float f; } v; v.u = u << 16;
    return v.f;
}

// ---------------------------------------------------------------------------
// Detect int32 vs int64 edge_index layout. is32 pre-zeroed; set 1 if any odd
// int32 word nonzero (-> genuine int32 pairs, not int64 low-words).
__global__ void k_detect(const int* __restrict__ ei32, int n_check,
                         int* __restrict__ is32) {
    int idx = blockIdx.x * 256 + threadIdx.x;
    int found = 0;
    for (int i = idx; i < n_check; i += 2048) {
        if (ei32[2 * i + 1] != 0) { found = 1; break; }
    }
    if (found) atomicOr(is32, 1);
}

// ---------------------------------------------------------------------------
// h_bf = bf16(x @ W1 + b1); 4 nodes/block, thread t of wave g -> feature t.
__global__ __launch_bounds__(256) void k_lin1(const float* __restrict__ x,
                                              const float* __restrict__ W1,
                                              const float* __restrict__ b1,
                                              ushort_t* __restrict__ h_bf, int N) {
    __shared__ float Ws[27 * 64];
    __shared__ float bs[64];
    __shared__ float xs[4 * 27];
    int tid = threadIdx.x;
    for (int i = tid; i < 27 * 64; i += 256) Ws[i] = W1[i];
    if (tid < 64) bs[tid] = b1[tid];
    int base = blockIdx.x * 4;
    if (tid < 108) {
        int gidx = base * 27 + tid;
        xs[tid] = (gidx < N * 27) ? x[gidx] : 0.f;
    }
    __syncthreads();
    int g = tid >> 6, t = tid & 63;
    int node = base + g;
    if (node < N) {
        float acc = bs[t];
        const float* xr = &xs[g * 27];
#pragma unroll
        for (int k = 0; k < 27; ++k) acc = fmaf(xr[k], Ws[k * 64 + t], acc);
        h_bf[(size_t)node * 64 + t] = f2bf(acc);
    }
}

// ---------------------------------------------------------------------------
// Bin edges into NB buckets of 512 consecutive dsts. Per block (4096 edges):
// LDS hist -> reserve contiguous runs (1 global atomic per nonempty bucket)
// -> burst-write packed ((dst&511)<<17)|src entries.
__global__ __launch_bounds__(256) void k_bin(const int* __restrict__ ei,
                                             const int* __restrict__ is32,
                                             int* __restrict__ bucketCnt,
                                             int* __restrict__ bucketArr,
                                             int E, int NB) {
    __shared__ int hist[MAXB];
    __shared__ int cur[MAXB];
    int tid = threadIdx.x;
    for (int i = tid; i < NB; i += 256) hist[i] = 0;
    __syncthreads();
    int e0 = blockIdx.x * 4096;
    int mode32 = *is32;
#pragma unroll
    for (int k = 0; k < 16; ++k) {
        int e = e0 + k * 256 + tid;
        if (e < E) {
            int dst = mode32 ? ei[E + e] : ((const int2*)ei)[E + e].x;
            atomicAdd(&hist[dst >> 9], 1);
        }
    }
    __syncthreads();
    for (int b = tid; b < NB; b += 256) {
        int c = hist[b];
        if (c > 0) cur[b] = b * LCAP + atomicAdd(&bucketCnt[b], c);
    }
    __syncthreads();
#pragma unroll
    for (int k = 0; k < 16; ++k) {
        int e = e0 + k * 256 + tid;
        if (e < E) {
            int src, dst;
            if (mode32) { src = ei[e]; dst = ei[E + e]; }
            else { src = ((const int2*)ei)[e].x; dst = ((const int2*)ei)[E + e].x; }
            int b = dst >> 9;
            int slot = atomicAdd(&cur[b], 1);
            if (slot < (b + 1) * LCAP)
                bucketArr[slot] = ((dst & 511) << 17) | src;
        }
    }
}

// ---------------------------------------------------------------------------
// Per-bucket LDS counting sort -> PADDED CSR segment at fixed stride PCAP.
// Every row padded to a multiple of 8 entries; pad entries point at dummy
// row N (zeros). All scattered stores land in LDS; global writes coalesced.
__global__ __launch_bounds__(256) void k_local(const int* __restrict__ bucketArr,
                                               const int* __restrict__ bucketCnt,
                                               int* __restrict__ src_padded,
                                               int* __restrict__ pstart,
                                               int* __restrict__ pdeg,
                                               int N) {
    __shared__ int hist[LB];
    __shared__ int cstart[LB];
    __shared__ int cursor[LB];
    __shared__ int ppos[LB];
    __shared__ int sdata[256];
    __shared__ int sorted[LCAP];
    int b = blockIdx.x, tid = threadIdx.x;
    for (int i = tid; i < LB; i += 256) hist[i] = 0;
    __syncthreads();
    int cnt = bucketCnt[b];
    if (cnt > LCAP) cnt = LCAP;
    const int* arr = bucketArr + (size_t)b * LCAP;
    for (int i = tid; i < cnt; i += 256) atomicAdd(&hist[arr[i] >> 17], 1);
    __syncthreads();
    // compact scan (pairs + Hillis-Steele over 256 partial sums)
    int v0 = hist[2 * tid], v1 = hist[2 * tid + 1];
    int psum = v0 + v1;
    sdata[tid] = psum;
    __syncthreads();
    for (int off = 1; off < 256; off <<= 1) {
        int add = (tid >= off) ? sdata[tid - off] : 0;
        __syncthreads();
        sdata[tid] += add;
        __syncthreads();
    }
    int cexcl = sdata[tid] - psum;
    cstart[2 * tid] = cexcl;           cursor[2 * tid] = cexcl;
    cstart[2 * tid + 1] = cexcl + v0;  cursor[2 * tid + 1] = cexcl + v0;
    // padded scan
    int p0 = (v0 + 7) & ~7, p1 = (v1 + 7) & ~7;
    int ppsum = p0 + p1;
    __syncthreads();
    sdata[tid] = ppsum;
    __syncthreads();
    for (int off = 1; off < 256; off <<= 1) {
        int add = (tid >= off) ? sdata[tid - off] : 0;
        __syncthreads();
        sdata[tid] += add;
        __syncthreads();
    }
    int pexcl = sdata[tid] - ppsum;
    ppos[2 * tid] = pexcl;
    ppos[2 * tid + 1] = pexcl + p0;
    __syncthreads();
    // scatter into compact LDS
    for (int i = tid; i < cnt; i += 256) {
        int pk = arr[i];                 // L2 hit (2nd read)
        int pos = atomicAdd(&cursor[pk >> 17], 1);
        sorted[pos] = pk & 0x1FFFF;
    }
    __syncthreads();
    // padded emit: 2 rows per thread, pad with dummy index N
    int* outp = src_padded + (size_t)b * PCAP;
    int n0 = b * LB;
    for (int ln = tid; ln < LB; ln += 256) {
        int h = hist[ln], cs = cstart[ln], pp = ppos[ln];
        int ph = (h + 7) & ~7;
        for (int j = 0; j < h; ++j) outp[pp + j] = sorted[cs + j];
        for (int j = h; j < ph; ++j) outp[pp + j] = N;
        int node = n0 + ln;
        if (node < N) {
            pstart[node] = b * PCAP + pp;
            pdeg[node] = ph >> 3;        // octet count
        }
    }
}

// ---------------------------------------------------------------------------
// agg_bf[n] = bf16( sum_{rows} h_bf[row] ) over padded CSR. One wave per
// node; each dwordx4 load fetches 8 rows (lane t: row sub=t>>3, 16B chunk
// off=t&7). Butterfly-reduce over lanes sharing off, pack, store 128B.
__global__ __launch_bounds__(256) void k_agg(const ushort_t* __restrict__ h_bf,
                                             const int* __restrict__ src_padded,
                                             const int* __restrict__ pstart,
                                             const int* __restrict__ pdeg,
                                             ushort_t* __restrict__ agg_bf, int N) {
    int w = (blockIdx.x * 256 + threadIdx.x) >> 6;
    int t = threadIdx.x & 63;
    if (w >= N) return;
    int start = pstart[w];
    int oct = pdeg[w];
    int sub = t >> 3, off = t & 7;
    const int* ip = src_padded + start + sub;
    float a0 = 0.f, a1 = 0.f, a2 = 0.f, a3 = 0.f;
    float a4 = 0.f, a5 = 0.f, a6 = 0.f, a7 = 0.f;
    int k = 0;
    for (; k + 2 <= oct; k += 2) {
        int r0 = ip[k * 8];
        int r1 = ip[k * 8 + 8];
        uint4 u = *(const uint4*)(h_bf + (size_t)r0 * 64 + off * 8);
        uint4 v = *(const uint4*)(h_bf + (size_t)r1 * 64 + off * 8);
        a0 += lo2f(u.x); a1 += hi2f(u.x); a2 += lo2f(u.y); a3 += hi2f(u.y);
        a4 += lo2f(u.z); a5 += hi2f(u.z); a6 += lo2f(u.w); a7 += hi2f(u.w);
        a0 += lo2f(v.x); a1 += hi2f(v.x); a2 += lo2f(v.y); a3 += hi2f(v.y);
        a4 += lo2f(v.z); a5 += hi2f(v.z); a6 += lo2f(v.w); a7 += hi2f(v.w);
    }
    if (k < oct) {
        int r0 = ip[k * 8];
        uint4 u = *(const uint4*)(h_bf + (size_t)r0 * 64 + off * 8);
        a0 += lo2f(u.x); a1 += hi2f(u.x); a2 += lo2f(u.y); a3 += hi2f(u.y);
        a4 += lo2f(u.z); a5 += hi2f(u.z); a6 += lo2f(u.w); a7 += hi2f(u.w);
    }
#pragma unroll
    for (int m = 8; m <= 32; m <<= 1) {
        a0 += __shfl_xor(a0, m); a1 += __shfl_xor(a1, m);
        a2 += __shfl_xor(a2, m); a3 += __shfl_xor(a3, m);
        a4 += __shfl_xor(a4, m); a5 += __shfl_xor(a5, m);
        a6 += __shfl_xor(a6, m); a7 += __shfl_xor(a7, m);
    }
    if (sub == 0) {
        uint4 d;
        d.x = ((unsigned)f2bf(a1) << 16) | f2bf(a0);
        d.y = ((unsigned)f2bf(a3) << 16) | f2bf(a2);
        d.z = ((unsigned)f2bf(a5) << 16) | f2bf(a4);
        d.w = ((unsigned)f2bf(a7) << 16) | f2bf(a6);
        *(uint4*)(agg_bf + (size_t)w * 64 + off * 8) = d;
    }
}

// ---------------------------------------------------------------------------
// MFMA tail: h2 = tanh(agg@Wrel + brel + h@Wroot); o = tanh(h2@W2 + b2);
// split + softplus + transposed store. One wave per 16-node tile.
__global__ __launch_bounds__(256) void k_tail(const ushort_t* __restrict__ h_bf,
                                              const ushort_t* __restrict__ agg_bf,
                                              const float* __restrict__ Wrel,
                                              const float* __restrict__ brel,
                                              const float* __restrict__ Wroot,
                                              const float* __restrict__ W2,
                                              const float* __restrict__ b2,
                                              float* __restrict__ out,
                                              int N, int ntiles) {
    __shared__ alignas(16) ushort_t WrelF[8 * 512];   // (kt*4+nt)*512 + lane*8 + j
    __shared__ alignas(16) ushort_t WrootF[8 * 512];
    __shared__ alignas(16) ushort_t W2F[2 * 512];     // kt*512 + lane*8 + j
    __shared__ alignas(16) ushort_t h2T[4][16 * 72];  // per-wave, row stride 72
    __shared__ float brelS[64];
    __shared__ float b2S[16];
    int tid = threadIdx.x;
    for (int i = tid; i < 4096; i += 256) {
        int j = i & 7, lane = (i >> 3) & 63, grp = i >> 9;
        int kt = grp >> 2, nt = grp & 3;
        int k = (kt << 5) + ((lane >> 4) << 3) + j;
        int n = (nt << 4) + (lane & 15);
        WrelF[i]  = f2bf(Wrel[k * 64 + n]);
        WrootF[i] = f2bf(Wroot[k * 64 + n]);
    }
    for (int i = tid; i < 1024; i += 256) {
        int j = i & 7, lane = (i >> 3) & 63, kt = i >> 9;
        int k = (kt << 5) + ((lane >> 4) << 3) + j;
        int n = (lane & 15);
        W2F[i] = f2bf(W2[k * 16 + n]);
    }
    if (tid < 64) brelS[tid] = brel[tid];
    if (tid < 16) b2S[tid] = b2[tid];
    __syncthreads();

    int lane = tid & 63;
    int wv = tid >> 6;
    int lrow = lane & 15;
    int lkg = lane >> 4;
    const bf16x8v* WrelV  = (const bf16x8v*)WrelF;
    const bf16x8v* WrootV = (const bf16x8v*)WrootF;
    const bf16x8v* W2V    = (const bf16x8v*)W2F;
    ushort_t* myT = h2T[wv];

    int tile = blockIdx.x * 4 + wv;
    if (tile >= ntiles) return;
    int rbase = tile * 16;
    int arow = rbase + lrow; if (arow >= N) arow = N - 1;
    const bf16x8v* aggV = (const bf16x8v*)(agg_bf + (size_t)arow * 64);
    const bf16x8v* hV   = (const bf16x8v*)(h_bf + (size_t)arow * 64);
    bf16x8v a0 = aggV[lkg], a1 = aggV[4 + lkg];
    bf16x8v x0 = hV[lkg],   x1 = hV[4 + lkg];

    f32x4 acc[4];
#pragma unroll
    for (int nt = 0; nt < 4; ++nt) { acc[nt] = (f32x4){0.f, 0.f, 0.f, 0.f}; }
#pragma unroll
    for (int nt = 0; nt < 4; ++nt) {
        acc[nt] = __builtin_amdgcn_mfma_f32_16x16x32_bf16(a0, WrelV[(0 * 4 + nt) * 64 + lane], acc[nt], 0, 0, 0);
        acc[nt] = __builtin_amdgcn_mfma_f32_16x16x32_bf16(a1, WrelV[(1 * 4 + nt) * 64 + lane], acc[nt], 0, 0, 0);
        acc[nt] = __builtin_amdgcn_mfma_f32_16x16x32_bf16(x0, WrootV[(0 * 4 + nt) * 64 + lane], acc[nt], 0, 0, 0);
        acc[nt] = __builtin_amdgcn_mfma_f32_16x16x32_bf16(x1, WrootV[(1 * 4 + nt) * 64 + lane], acc[nt], 0, 0, 0);
    }
#pragma unroll
    for (int nt = 0; nt < 4; ++nt) {
        int feat = nt * 16 + lrow;
        float bias = brelS[feat];
#pragma unroll
        for (int r = 0; r < 4; ++r) {
            int noderow = lkg * 4 + r;
            myT[noderow * 72 + feat] = f2bf(tanhf(acc[nt][r] + bias));
        }
    }
    __threadfence_block();
    const bf16x8v* h2V = (const bf16x8v*)myT;
    bf16x8v p0 = h2V[lrow * 9 + lkg];
    bf16x8v p1 = h2V[lrow * 9 + 4 + lkg];
    f32x4 acc2 = (f32x4){0.f, 0.f, 0.f, 0.f};
    acc2 = __builtin_amdgcn_mfma_f32_16x16x32_bf16(p0, W2V[0 * 64 + lane], acc2, 0, 0, 0);
    acc2 = __builtin_amdgcn_mfma_f32_16x16x32_bf16(p1, W2V[1 * 64 + lane], acc2, 0, 0, 0);

    int feat = lrow;
    float bias2 = b2S[feat];
#pragma unroll
    for (int r = 0; r < 4; ++r) {
        int node = rbase + lkg * 4 + r;
        float o = tanhf(acc2[r] + bias2);
        if (feat >= 8) {
            float sp = log1pf(expf(o + SP_BIAS));
            o = fmaxf(sp, 1e-4f);
        }
        if (node < N) out[(size_t)feat * N + node] = o;
    }
}

// ---------------------------------------------------------------------------
extern "C" void kernel_launch(void* const* d_in, const int* in_sizes, int n_in,
                              void* d_out, int out_size, void* d_ws, size_t ws_size,
                              hipStream_t stream) {
    const float* x    = (const float*)d_in[0];
    const int*   ei   = (const int*)d_in[1];
    const float* W1   = (const float*)d_in[2];
    const float* b1   = (const float*)d_in[3];
    const float* Wrel = (const float*)d_in[4];
    const float* brel = (const float*)d_in[5];
    const float* Wroot= (const float*)d_in[6];
    const float* W2   = (const float*)d_in[7];
    const float* b2   = (const float*)d_in[8];

    int N = in_sizes[0] / 27;
    int E = in_sizes[1] / 2;

    int NB = (N + LB - 1) / LB;     // buckets of 512 dsts

    ushort_t* h_bf       = (ushort_t*)d_ws;                  // (N+1)*64 bf16
    ushort_t* agg_bf     = h_bf + (size_t)(N + 1) * 64;      // N*64 bf16
    int*      bucketArr  = (int*)(agg_bf + (size_t)N * 64);  // NB*LCAP int
    int*      src_padded = bucketArr + (size_t)NB * LCAP;    // NB*PCAP int
    int*      pstart     = src_padded + (size_t)NB * PCAP;   // N int
    int*      pdeg       = pstart + N;                       // N int
    int*      bucketCnt  = pdeg + N;                         // NB int (zeroed)
    int*      is32       = bucketCnt + NB;                   // 1 int (zeroed)

    int ntiles16 = (N + 15) / 16;

    hipMemsetAsync(bucketCnt, 0, (size_t)(NB + 1) * sizeof(int), stream);
    hipMemsetAsync(h_bf + (size_t)N * 64, 0, 64 * sizeof(ushort_t), stream);
    int ncheck = 2 * E < 65536 ? 2 * E : 65536;
    k_detect<<<8, 256, 0, stream>>>(ei, ncheck, is32);
    k_lin1<<<(N + 3) / 4, 256, 0, stream>>>(x, W1, b1, h_bf, N);
    k_bin<<<(E + 4095) / 4096, 256, 0, stream>>>(ei, is32, bucketCnt, bucketArr,
                                                 E, NB);
    k_local<<<NB, 256, 0, stream>>>(bucketArr, bucketCnt, src_padded,
                                    pstart, pdeg, N);
    k_agg<<<(N + 3) / 4, 256, 0, stream>>>(h_bf, src_padded, pstart, pdeg,
                                           agg_bf, N);
    k_tail<<<(ntiles16 + 3) / 4, 256, 0, stream>>>(h_bf, agg_bf, Wrel, brel, Wroot,
                                                   W2, b2, (float*)d_out, N, ntiles16);
}

// Round 8
// 145.544 us; speedup vs baseline: 5.4158x; 1.0967x over previous
//
#include <hip/hip_runtime.h>
#include <hip/hip_bf16.h>
#include <math.h>

typedef unsigned short ushort_t;
typedef float f32x4 __attribute__((ext_vector_type(4)));
typedef short bf16x8v __attribute__((ext_vector_type(8)));

static constexpr float SP_BIAS = 0.5413248546129181f; // log(expm1(1.0))
#define LB   512     // nodes per bucket (9-bit local index)
#define LCAP 12288   // max compact entries per bucket (mean 8163)
#define PCAP 16384   // fixed padded stride per bucket (>= LCAP + 512*7)
#define MAXB 256     // max buckets -> N <= 131072 (17-bit src pack)

__device__ __forceinline__ ushort_t f2bf(float f) {
    union { float f; unsigned u; } v; v.f = f;
    unsigned r = v.u + 0x7FFFu + ((v.u >> 16) & 1u);   // RNE
    return (ushort_t)(r >> 16);
}
__device__ __forceinline__ float bf2f(ushort_t u) {
    union { unsigned u; float f; } v; v.u = ((unsigned)u) << 16;
    return v.f;
}
__device__ __forceinline__ float hi2f(unsigned u) {
    union { unsigned u; float f; } v; v.u = u & 0xFFFF0000u;
    return v.f;
}
__device__ __forceinline__ float lo2f(unsigned u) {
    union { unsigned u; float f; } v; v.u = u << 16;
    return v.f;
}

// ---------------------------------------------------------------------------
// One-block init: zero bucketCnt + dummy h-row, and detect int32 vs int64
// edge layout (int64 -> every odd int32 word is 0 for values < 2^31).
__global__ __launch_bounds__(256) void k_init(const int* __restrict__ ei32,
                                              int n_check, int* __restrict__ is32,
                                              int* __restrict__ bucketCnt, int NB,
                                              int* __restrict__ dummyRow) {
    __shared__ int s;
    int tid = threadIdx.x;
    if (tid == 0) s = 0;
    for (int i = tid; i < NB; i += 256) bucketCnt[i] = 0;
    if (tid < 32) dummyRow[tid] = 0;
    __syncthreads();
    int found = 0;
    for (int i = tid; i < n_check; i += 256) {
        if (ei32[2 * i + 1] != 0) { found = 1; break; }
    }
    if (found) atomicOr(&s, 1);
    __syncthreads();
    if (tid == 0) *is32 = s;
}

// ---------------------------------------------------------------------------
// h_bf = bf16(x @ W1 + b1). Persistent grid-stride: weights staged in LDS
// once per block, then ~nchunks/grid chunks of 4 nodes each.
__global__ __launch_bounds__(256) void k_lin1(const float* __restrict__ x,
                                              const float* __restrict__ W1,
                                              const float* __restrict__ b1,
                                              ushort_t* __restrict__ h_bf,
                                              int N, int nchunks) {
    __shared__ float Ws[27 * 64];
    __shared__ float bs[64];
    __shared__ float xs[4 * 27];
    int tid = threadIdx.x;
    for (int i = tid; i < 27 * 64; i += 256) Ws[i] = W1[i];
    if (tid < 64) bs[tid] = b1[tid];
    int g = tid >> 6, t = tid & 63;
    for (int chunk = blockIdx.x; chunk < nchunks; chunk += gridDim.x) {
        int base = chunk * 4;
        __syncthreads();
        if (tid < 108) {
            int gidx = base * 27 + tid;
            xs[tid] = (gidx < N * 27) ? x[gidx] : 0.f;
        }
        __syncthreads();
        int node = base + g;
        if (node < N) {
            float acc = bs[t];
            const float* xr = &xs[g * 27];
#pragma unroll
            for (int k = 0; k < 27; ++k) acc = fmaf(xr[k], Ws[k * 64 + t], acc);
            h_bf[(size_t)node * 64 + t] = f2bf(acc);
        }
    }
}

// ---------------------------------------------------------------------------
// Bin edges into NB buckets of 512 consecutive dsts. Per block (4096 edges):
// LDS hist -> reserve contiguous runs (1 global atomic per nonempty bucket)
// -> burst-write packed ((dst&511)<<17)|src entries.
__global__ __launch_bounds__(256) void k_bin(const int* __restrict__ ei,
                                             const int* __restrict__ is32,
                                             int* __restrict__ bucketCnt,
                                             int* __restrict__ bucketArr,
                                             int E, int NB) {
    __shared__ int hist[MAXB];
    __shared__ int cur[MAXB];
    int tid = threadIdx.x;
    for (int i = tid; i < NB; i += 256) hist[i] = 0;
    __syncthreads();
    int e0 = blockIdx.x * 4096;
    int mode32 = *is32;
#pragma unroll
    for (int k = 0; k < 16; ++k) {
        int e = e0 + k * 256 + tid;
        if (e < E) {
            int dst = mode32 ? ei[E + e] : ((const int2*)ei)[E + e].x;
            atomicAdd(&hist[dst >> 9], 1);
        }
    }
    __syncthreads();
    for (int b = tid; b < NB; b += 256) {
        int c = hist[b];
        if (c > 0) cur[b] = b * LCAP + atomicAdd(&bucketCnt[b], c);
    }
    __syncthreads();
#pragma unroll
    for (int k = 0; k < 16; ++k) {
        int e = e0 + k * 256 + tid;
        if (e < E) {
            int src, dst;
            if (mode32) { src = ei[e]; dst = ei[E + e]; }
            else { src = ((const int2*)ei)[e].x; dst = ((const int2*)ei)[E + e].x; }
            int b = dst >> 9;
            int slot = atomicAdd(&cur[b], 1);
            if (slot < (b + 1) * LCAP)
                bucketArr[slot] = ((dst & 511) << 17) | src;
        }
    }
}

// ---------------------------------------------------------------------------
// Per-bucket LDS counting sort -> PADDED CSR segment at fixed stride PCAP.
// Every row padded to a multiple of 8 entries; pad entries point at dummy
// row N (zeros). All scattered stores land in LDS; global writes coalesced.
__global__ __launch_bounds__(256) void k_local(const int* __restrict__ bucketArr,
                                               const int* __restrict__ bucketCnt,
                                               int* __restrict__ src_padded,
                                               int* __restrict__ pstart,
                                               int* __restrict__ pdeg,
                                               int N) {
    __shared__ int hist[LB];
    __shared__ int cstart[LB];
    __shared__ int cursor[LB];
    __shared__ int ppos[LB];
    __shared__ int sdata[256];
    __shared__ int sorted[LCAP];
    int b = blockIdx.x, tid = threadIdx.x;
    for (int i = tid; i < LB; i += 256) hist[i] = 0;
    __syncthreads();
    int cnt = bucketCnt[b];
    if (cnt > LCAP) cnt = LCAP;
    const int* arr = bucketArr + (size_t)b * LCAP;
    for (int i = tid; i < cnt; i += 256) atomicAdd(&hist[arr[i] >> 17], 1);
    __syncthreads();
    // compact scan (pairs + Hillis-Steele over 256 partial sums)
    int v0 = hist[2 * tid], v1 = hist[2 * tid + 1];
    int psum = v0 + v1;
    sdata[tid] = psum;
    __syncthreads();
    for (int off = 1; off < 256; off <<= 1) {
        int add = (tid >= off) ? sdata[tid - off] : 0;
        __syncthreads();
        sdata[tid] += add;
        __syncthreads();
    }
    int cexcl = sdata[tid] - psum;
    cstart[2 * tid] = cexcl;           cursor[2 * tid] = cexcl;
    cstart[2 * tid + 1] = cexcl + v0;  cursor[2 * tid + 1] = cexcl + v0;
    // padded scan
    int p0 = (v0 + 7) & ~7, p1 = (v1 + 7) & ~7;
    int ppsum = p0 + p1;
    __syncthreads();
    sdata[tid] = ppsum;
    __syncthreads();
    for (int off = 1; off < 256; off <<= 1) {
        int add = (tid >= off) ? sdata[tid - off] : 0;
        __syncthreads();
        sdata[tid] += add;
        __syncthreads();
    }
    int pexcl = sdata[tid] - ppsum;
    ppos[2 * tid] = pexcl;
    ppos[2 * tid + 1] = pexcl + p0;
    __syncthreads();
    // scatter into compact LDS
    for (int i = tid; i < cnt; i += 256) {
        int pk = arr[i];                 // L2 hit (2nd read)
        int pos = atomicAdd(&cursor[pk >> 17], 1);
        sorted[pos] = pk & 0x1FFFF;
    }
    __syncthreads();
    // padded emit: pad with dummy index N
    int* outp = src_padded + (size_t)b * PCAP;
    int n0 = b * LB;
    for (int ln = tid; ln < LB; ln += 256) {
        int h = hist[ln], cs = cstart[ln], pp = ppos[ln];
        int ph = (h + 7) & ~7;
        for (int j = 0; j < h; ++j) outp[pp + j] = sorted[cs + j];
        for (int j = h; j < ph; ++j) outp[pp + j] = N;
        int node = n0 + ln;
        if (node < N) {
            pstart[node] = b * PCAP + pp;
            pdeg[node] = ph >> 3;        // octet count
        }
    }
}

// ---------------------------------------------------------------------------
// agg_bf[n] = bf16( sum_{rows} h_bf[row] ) over padded CSR. One wave per
// node; each dwordx4 load fetches 8 rows (lane t: row sub=t>>3, 16B chunk
// off=t&7). Butterfly-reduce over lanes sharing off, pack, store 128B.
__global__ __launch_bounds__(256) void k_agg(const ushort_t* __restrict__ h_bf,
                                             const int* __restrict__ src_padded,
                                             const int* __restrict__ pstart,
                                             const int* __restrict__ pdeg,
                                             ushort_t* __restrict__ agg_bf, int N) {
    int w = (blockIdx.x * 256 + threadIdx.x) >> 6;
    int t = threadIdx.x & 63;
    if (w >= N) return;
    int start = pstart[w];
    int oct = pdeg[w];
    int sub = t >> 3, off = t & 7;
    const int* ip = src_padded + start + sub;
    float a0 = 0.f, a1 = 0.f, a2 = 0.f, a3 = 0.f;
    float a4 = 0.f, a5 = 0.f, a6 = 0.f, a7 = 0.f;
    int k = 0;
    for (; k + 2 <= oct; k += 2) {
        int r0 = ip[k * 8];
        int r1 = ip[k * 8 + 8];
        uint4 u = *(const uint4*)(h_bf + (size_t)r0 * 64 + off * 8);
        uint4 v = *(const uint4*)(h_bf + (size_t)r1 * 64 + off * 8);
        a0 += lo2f(u.x); a1 += hi2f(u.x); a2 += lo2f(u.y); a3 += hi2f(u.y);
        a4 += lo2f(u.z); a5 += hi2f(u.z); a6 += lo2f(u.w); a7 += hi2f(u.w);
        a0 += lo2f(v.x); a1 += hi2f(v.x); a2 += lo2f(v.y); a3 += hi2f(v.y);
        a4 += lo2f(v.z); a5 += hi2f(v.z); a6 += lo2f(v.w); a7 += hi2f(v.w);
    }
    if (k < oct) {
        int r0 = ip[k * 8];
        uint4 u = *(const uint4*)(h_bf + (size_t)r0 * 64 + off * 8);
        a0 += lo2f(u.x); a1 += hi2f(u.x); a2 += lo2f(u.y); a3 += hi2f(u.y);
        a4 += lo2f(u.z); a5 += hi2f(u.z); a6 += lo2f(u.w); a7 += hi2f(u.w);
    }
#pragma unroll
    for (int m = 8; m <= 32; m <<= 1) {
        a0 += __shfl_xor(a0, m); a1 += __shfl_xor(a1, m);
        a2 += __shfl_xor(a2, m); a3 += __shfl_xor(a3, m);
        a4 += __shfl_xor(a4, m); a5 += __shfl_xor(a5, m);
        a6 += __shfl_xor(a6, m); a7 += __shfl_xor(a7, m);
    }
    if (sub == 0) {
        uint4 d;
        d.x = ((unsigned)f2bf(a1) << 16) | f2bf(a0);
        d.y = ((unsigned)f2bf(a3) << 16) | f2bf(a2);
        d.z = ((unsigned)f2bf(a5) << 16) | f2bf(a4);
        d.w = ((unsigned)f2bf(a7) << 16) | f2bf(a6);
        *(uint4*)(agg_bf + (size_t)w * 64 + off * 8) = d;
    }
}

// ---------------------------------------------------------------------------
// MFMA tail: h2 = tanh(agg@Wrel + brel + h@Wroot); o = tanh(h2@W2 + b2);
// split + softplus + transposed store. One wave per 16-node tile.
__global__ __launch_bounds__(256) void k_tail(const ushort_t* __restrict__ h_bf,
                                              const ushort_t* __restrict__ agg_bf,
                                              const float* __restrict__ Wrel,
                                              const float* __restrict__ brel,
                                              const float* __restrict__ Wroot,
                                              const float* __restrict__ W2,
                                              const float* __restrict__ b2,
                                              float* __restrict__ out,
                                              int N, int ntiles) {
    __shared__ alignas(16) ushort_t WrelF[8 * 512];   // (kt*4+nt)*512 + lane*8 + j
    __shared__ alignas(16) ushort_t WrootF[8 * 512];
    __shared__ alignas(16) ushort_t W2F[2 * 512];     // kt*512 + lane*8 + j
    __shared__ alignas(16) ushort_t h2T[4][16 * 72];  // per-wave, row stride 72
    __shared__ float brelS[64];
    __shared__ float b2S[16];
    int tid = threadIdx.x;
    for (int i = tid; i < 4096; i += 256) {
        int j = i & 7, lane = (i >> 3) & 63, grp = i >> 9;
        int kt = grp >> 2, nt = grp & 3;
        int k = (kt << 5) + ((lane >> 4) << 3) + j;
        int n = (nt << 4) + (lane & 15);
        WrelF[i]  = f2bf(Wrel[k * 64 + n]);
        WrootF[i] = f2bf(Wroot[k * 64 + n]);
    }
    for (int i = tid; i < 1024; i += 256) {
        int j = i & 7, lane = (i >> 3) & 63, kt = i >> 9;
        int k = (kt << 5) + ((lane >> 4) << 3) + j;
        int n = (lane & 15);
        W2F[i] = f2bf(W2[k * 16 + n]);
    }
    if (tid < 64) brelS[tid] = brel[tid];
    if (tid < 16) b2S[tid] = b2[tid];
    __syncthreads();

    int lane = tid & 63;
    int wv = tid >> 6;
    int lrow = lane & 15;
    int lkg = lane >> 4;
    const bf16x8v* WrelV  = (const bf16x8v*)WrelF;
    const bf16x8v* WrootV = (const bf16x8v*)WrootF;
    const bf16x8v* W2V    = (const bf16x8v*)W2F;
    ushort_t* myT = h2T[wv];

    int tile = blockIdx.x * 4 + wv;
    if (tile >= ntiles) return;
    int rbase = tile * 16;
    int arow = rbase + lrow; if (arow >= N) arow = N - 1;
    const bf16x8v* aggV = (const bf16x8v*)(agg_bf + (size_t)arow * 64);
    const bf16x8v* hV   = (const bf16x8v*)(h_bf + (size_t)arow * 64);
    bf16x8v a0 = aggV[lkg], a1 = aggV[4 + lkg];
    bf16x8v x0 = hV[lkg],   x1 = hV[4 + lkg];

    f32x4 acc[4];
#pragma unroll
    for (int nt = 0; nt < 4; ++nt) { acc[nt] = (f32x4){0.f, 0.f, 0.f, 0.f}; }
#pragma unroll
    for (int nt = 0; nt < 4; ++nt) {
        acc[nt] = __builtin_amdgcn_mfma_f32_16x16x32_bf16(a0, WrelV[(0 * 4 + nt) * 64 + lane], acc[nt], 0, 0, 0);
        acc[nt] = __builtin_amdgcn_mfma_f32_16x16x32_bf16(a1, WrelV[(1 * 4 + nt) * 64 + lane], acc[nt], 0, 0, 0);
        acc[nt] = __builtin_amdgcn_mfma_f32_16x16x32_bf16(x0, WrootV[(0 * 4 + nt) * 64 + lane], acc[nt], 0, 0, 0);
        acc[nt] = __builtin_amdgcn_mfma_f32_16x16x32_bf16(x1, WrootV[(1 * 4 + nt) * 64 + lane], acc[nt], 0, 0, 0);
    }
#pragma unroll
    for (int nt = 0; nt < 4; ++nt) {
        int feat = nt * 16 + lrow;
        float bias = brelS[feat];
#pragma unroll
        for (int r = 0; r < 4; ++r) {
            int noderow = lkg * 4 + r;
            myT[noderow * 72 + feat] = f2bf(tanhf(acc[nt][r] + bias));
        }
    }
    __threadfence_block();
    const bf16x8v* h2V = (const bf16x8v*)myT;
    bf16x8v p0 = h2V[lrow * 9 + lkg];
    bf16x8v p1 = h2V[lrow * 9 + 4 + lkg];
    f32x4 acc2 = (f32x4){0.f, 0.f, 0.f, 0.f};
    acc2 = __builtin_amdgcn_mfma_f32_16x16x32_bf16(p0, W2V[0 * 64 + lane], acc2, 0, 0, 0);
    acc2 = __builtin_amdgcn_mfma_f32_16x16x32_bf16(p1, W2V[1 * 64 + lane], acc2, 0, 0, 0);

    int feat = lrow;
    float bias2 = b2S[feat];
#pragma unroll
    for (int r = 0; r < 4; ++r) {
        int node = rbase + lkg * 4 + r;
        float o = tanhf(acc2[r] + bias2);
        if (feat >= 8) {
            float sp = log1pf(expf(o + SP_BIAS));
            o = fmaxf(sp, 1e-4f);
        }
        if (node < N) out[(size_t)feat * N + node] = o;
    }
}

// ---------------------------------------------------------------------------
extern "C" void kernel_launch(void* const* d_in, const int* in_sizes, int n_in,
                              void* d_out, int out_size, void* d_ws, size_t ws_size,
                              hipStream_t stream) {
    const float* x    = (const float*)d_in[0];
    const int*   ei   = (const int*)d_in[1];
    const float* W1   = (const float*)d_in[2];
    const float* b1   = (const float*)d_in[3];
    const float* Wrel = (const float*)d_in[4];
    const float* brel = (const float*)d_in[5];
    const float* Wroot= (const float*)d_in[6];
    const float* W2   = (const float*)d_in[7];
    const float* b2   = (const float*)d_in[8];

    int N = in_sizes[0] / 27;
    int E = in_sizes[1] / 2;

    int NB = (N + LB - 1) / LB;     // buckets of 512 dsts

    ushort_t* h_bf       = (ushort_t*)d_ws;                  // (N+1)*64 bf16
    ushort_t* agg_bf     = h_bf + (size_t)(N + 1) * 64;      // N*64 bf16
    int*      bucketArr  = (int*)(agg_bf + (size_t)N * 64);  // NB*LCAP int
    int*      src_padded = bucketArr + (size_t)NB * LCAP;    // NB*PCAP int
    int*      pstart     = src_padded + (size_t)NB * PCAP;   // N int
    int*      pdeg       = pstart + N;                       // N int
    int*      bucketCnt  = pdeg + N;                         // NB int
    int*      is32       = bucketCnt + NB;                   // 1 int

    int ntiles16 = (N + 15) / 16;
    int nchunks4 = (N + 3) / 4;

    int ncheck = E < 8192 ? E : 8192;
    k_init<<<1, 256, 0, stream>>>(ei, ncheck, is32, bucketCnt, NB,
                                  (int*)(h_bf + (size_t)N * 64));
    k_lin1<<<2048, 256, 0, stream>>>(x, W1, b1, h_bf, N, nchunks4);
    k_bin<<<(E + 4095) / 4096, 256, 0, stream>>>(ei, is32, bucketCnt, bucketArr,
                                                 E, NB);
    k_local<<<NB, 256, 0, stream>>>(bucketArr, bucketCnt, src_padded,
                                    pstart, pdeg, N);
    k_agg<<<nchunks4, 256, 0, stream>>>(h_bf, src_padded, pstart, pdeg,
                                        agg_bf, N);
    k_tail<<<(ntiles16 + 3) / 4, 256, 0, stream>>>(h_bf, agg_bf, Wrel, brel, Wroot,
                                                   W2, b2, (float*)d_out, N, ntiles16);
}

// Round 9
// 141.373 us; speedup vs baseline: 5.5756x; 1.0295x over previous
//
#include <hip/hip_runtime.h>
#include <hip/hip_bf16.h>
#include <math.h>

typedef unsigned short ushort_t;
typedef float f32x4 __attribute__((ext_vector_type(4)));
typedef short bf16x8v __attribute__((ext_vector_type(8)));

static constexpr float SP_BIAS = 0.5413248546129181f; // log(expm1(1.0))
#define LB   512     // nodes per bucket (9-bit local index)
#define LCAP 12288   // max compact entries per bucket (mean 8163)
#define PCAP 16384   // fixed padded stride per bucket
#define MAXB 256     // max buckets -> N <= 131072 (17-bit src pack)
#define EPB  4096    // edges per k_bin block

__device__ __forceinline__ ushort_t f2bf(float f) {
    union { float f; unsigned u; } v; v.f = f;
    unsigned r = v.u + 0x7FFFu + ((v.u >> 16) & 1u);   // RNE
    return (ushort_t)(r >> 16);
}
__device__ __forceinline__ float bf2f(ushort_t u) {
    union { unsigned u; float f; } v; v.u = ((unsigned)u) << 16;
    return v.f;
}
__device__ __forceinline__ float hi2f(unsigned u) {
    union { unsigned u; float f; } v; v.u = u & 0xFFFF0000u;
    return v.f;
}
__device__ __forceinline__ float lo2f(unsigned u) {
    union { unsigned u; float f; } v; v.u = u << 16;
    return v.f;
}

// ---------------------------------------------------------------------------
// Multi-block init. Block 0: zero bucketCnt + dummy h-row, detect int32 vs
// int64 edge layout. Blocks 1..36: pre-convert Wrel/Wroot/W2 into bf16 MFMA
// fragment arrays (done once here instead of per-k_tail-block).
__global__ __launch_bounds__(256) void k_init(const int* __restrict__ ei32,
                                              int n_check, int* __restrict__ is32,
                                              int* __restrict__ bucketCnt, int NB,
                                              int* __restrict__ dummyRow,
                                              const float* __restrict__ Wrel,
                                              const float* __restrict__ Wroot,
                                              const float* __restrict__ W2,
                                              ushort_t* __restrict__ wrelF,
                                              ushort_t* __restrict__ wrootF,
                                              ushort_t* __restrict__ w2F) {
    int b = blockIdx.x, tid = threadIdx.x;
    if (b == 0) {
        __shared__ int s;
        if (tid == 0) s = 0;
        for (int i = tid; i < NB; i += 256) bucketCnt[i] = 0;
        if (tid < 32) dummyRow[tid] = 0;
        __syncthreads();
        int found = 0;
        for (int i = tid; i < n_check; i += 256) {
            if (ei32[2 * i + 1] != 0) { found = 1; break; }
        }
        if (found) atomicOr(&s, 1);
        __syncthreads();
        if (tid == 0) *is32 = s;
    } else if (b <= 32) {
        // fragment layout: i = grp*512 + lane*8 + j ; grp = kt*4+nt
        int i = (b - 1 - (b > 16 ? 16 : 0)) * 256 + tid;
        int j = i & 7, lane = (i >> 3) & 63, grp = i >> 9;
        int kt = grp >> 2, nt = grp & 3;
        int k = (kt << 5) + ((lane >> 4) << 3) + j;
        int n = (nt << 4) + (lane & 15);
        if (b <= 16) wrelF[i]  = f2bf(Wrel[k * 64 + n]);
        else         wrootF[i] = f2bf(Wroot[k * 64 + n]);
    } else {  // b = 33..36 : W2 fragments (1024 entries)
        int i = (b - 33) * 256 + tid;
        int j = i & 7, lane = (i >> 3) & 63, kt = i >> 9;
        int k = (kt << 5) + ((lane >> 4) << 3) + j;
        int n = (lane & 15);
        w2F[i] = f2bf(W2[k * 16 + n]);
    }
}

// ---------------------------------------------------------------------------
// h_bf = bf16(x @ W1 + b1). Persistent grid-stride, weights staged once.
__global__ __launch_bounds__(256) void k_lin1(const float* __restrict__ x,
                                              const float* __restrict__ W1,
                                              const float* __restrict__ b1,
                                              ushort_t* __restrict__ h_bf,
                                              int N, int nchunks) {
    __shared__ float Ws[27 * 64];
    __shared__ float bs[64];
    __shared__ float xs[4 * 27];
    int tid = threadIdx.x;
    for (int i = tid; i < 27 * 64; i += 256) Ws[i] = W1[i];
    if (tid < 64) bs[tid] = b1[tid];
    int g = tid >> 6, t = tid & 63;
    for (int chunk = blockIdx.x; chunk < nchunks; chunk += gridDim.x) {
        int base = chunk * 4;
        __syncthreads();
        if (tid < 108) {
            int gidx = base * 27 + tid;
            xs[tid] = (gidx < N * 27) ? x[gidx] : 0.f;
        }
        __syncthreads();
        int node = base + g;
        if (node < N) {
            float acc = bs[t];
            const float* xr = &xs[g * 27];
#pragma unroll
            for (int k = 0; k < 27; ++k) acc = fmaf(xr[k], Ws[k * 64 + t], acc);
            h_bf[(size_t)node * 64 + t] = f2bf(acc);
        }
    }
}

// ---------------------------------------------------------------------------
// Single-pass bin: stage this block's edges in LDS, then hist -> reserve ->
// scatter packed ((dst&511)<<17)|src entries, all from LDS (no 2nd global read).
__global__ __launch_bounds__(256) void k_bin(const int* __restrict__ ei,
                                             const int* __restrict__ is32,
                                             int* __restrict__ bucketCnt,
                                             int* __restrict__ bucketArr,
                                             int E, int NB) {
    __shared__ int hist[MAXB];
    __shared__ int cur[MAXB];
    __shared__ int s_dst[EPB];
    __shared__ int s_src[EPB];
    int tid = threadIdx.x;
    for (int i = tid; i < NB; i += 256) hist[i] = 0;
    __syncthreads();
    int e0 = blockIdx.x * EPB;
    int cnt = E - e0; if (cnt > EPB) cnt = EPB;
    if (*is32) {
        for (int i = tid; i < cnt; i += 256) {
            s_src[i] = ei[e0 + i];
            s_dst[i] = ei[E + e0 + i];
        }
    } else {
        const int2* p = (const int2*)ei;
        for (int i = tid; i < cnt; i += 256) {
            s_src[i] = p[e0 + i].x;
            s_dst[i] = p[E + e0 + i].x;
        }
    }
    __syncthreads();
    for (int i = tid; i < cnt; i += 256) atomicAdd(&hist[s_dst[i] >> 9], 1);
    __syncthreads();
    for (int b = tid; b < NB; b += 256) {
        int c = hist[b];
        if (c > 0) cur[b] = b * LCAP + atomicAdd(&bucketCnt[b], c);
    }
    __syncthreads();
    for (int i = tid; i < cnt; i += 256) {
        int d = s_dst[i];
        int b = d >> 9;
        int slot = atomicAdd(&cur[b], 1);
        if (slot < (b + 1) * LCAP)
            bucketArr[slot] = ((d & 511) << 17) | s_src[i];
    }
}

// ---------------------------------------------------------------------------
// Per-bucket LDS counting sort -> PADDED CSR segment at fixed stride PCAP.
// Rows padded to multiple of 8 entries; pads point at dummy row N (zeros).
__global__ __launch_bounds__(256) void k_local(const int* __restrict__ bucketArr,
                                               const int* __restrict__ bucketCnt,
                                               int* __restrict__ src_padded,
                                               int* __restrict__ pstart,
                                               int* __restrict__ pdeg,
                                               int N) {
    __shared__ int hist[LB];
    __shared__ int cstart[LB];
    __shared__ int cursor[LB];
    __shared__ int ppos[LB];
    __shared__ int sdata[256];
    __shared__ int sorted[LCAP];
    int b = blockIdx.x, tid = threadIdx.x;
    for (int i = tid; i < LB; i += 256) hist[i] = 0;
    __syncthreads();
    int cnt = bucketCnt[b];
    if (cnt > LCAP) cnt = LCAP;
    const int* arr = bucketArr + (size_t)b * LCAP;
    for (int i = tid; i < cnt; i += 256) atomicAdd(&hist[arr[i] >> 17], 1);
    __syncthreads();
    int v0 = hist[2 * tid], v1 = hist[2 * tid + 1];
    int psum = v0 + v1;
    sdata[tid] = psum;
    __syncthreads();
    for (int off = 1; off < 256; off <<= 1) {
        int add = (tid >= off) ? sdata[tid - off] : 0;
        __syncthreads();
        sdata[tid] += add;
        __syncthreads();
    }
    int cexcl = sdata[tid] - psum;
    cstart[2 * tid] = cexcl;           cursor[2 * tid] = cexcl;
    cstart[2 * tid + 1] = cexcl + v0;  cursor[2 * tid + 1] = cexcl + v0;
    int p0 = (v0 + 7) & ~7, p1 = (v1 + 7) & ~7;
    int ppsum = p0 + p1;
    __syncthreads();
    sdata[tid] = ppsum;
    __syncthreads();
    for (int off = 1; off < 256; off <<= 1) {
        int add = (tid >= off) ? sdata[tid - off] : 0;
        __syncthreads();
        sdata[tid] += add;
        __syncthreads();
    }
    int pexcl = sdata[tid] - ppsum;
    ppos[2 * tid] = pexcl;
    ppos[2 * tid + 1] = pexcl + p0;
    __syncthreads();
    for (int i = tid; i < cnt; i += 256) {
        int pk = arr[i];
        int pos = atomicAdd(&cursor[pk >> 17], 1);
        sorted[pos] = pk & 0x1FFFF;
    }
    __syncthreads();
    int* outp = src_padded + (size_t)b * PCAP;
    int n0 = b * LB;
    for (int ln = tid; ln < LB; ln += 256) {
        int h = hist[ln], cs = cstart[ln], pp = ppos[ln];
        int ph = (h + 7) & ~7;
        for (int j = 0; j < h; ++j) outp[pp + j] = sorted[cs + j];
        for (int j = h; j < ph; ++j) outp[pp + j] = N;
        int node = n0 + ln;
        if (node < N) {
            pstart[node] = b * PCAP + pp;
            pdeg[node] = ph >> 3;        // octet count
        }
    }
}

// ---------------------------------------------------------------------------
// agg_bf[n] = bf16( sum rows ) over padded CSR. One wave per node. Quad
// scheme: each dwordx2 load covers 4 rows (lane t: row sub=t>>4, 8B chunk
// off=t&15). Only 2 butterfly rounds x 4 accs = 8 shuffles per node
// (vs 24 for octet scheme). 2-deep unroll -> 4 loads in flight.
__global__ __launch_bounds__(256) void k_agg(const ushort_t* __restrict__ h_bf,
                                             const int* __restrict__ src_padded,
                                             const int* __restrict__ pstart,
                                             const int* __restrict__ pdeg,
                                             ushort_t* __restrict__ agg_bf, int N) {
    int w = (blockIdx.x * 256 + threadIdx.x) >> 6;
    int t = threadIdx.x & 63;
    if (w >= N) return;
    int start = pstart[w];
    int nq = pdeg[w] * 2;          // quads (pdeg counts octets)
    int sub = t >> 4, off = t & 15;
    const int* ip = src_padded + start + sub;
    float a0 = 0.f, a1 = 0.f, a2 = 0.f, a3 = 0.f;
    int k = 0;
    for (; k + 2 <= nq; k += 2) {
        int r0 = ip[k * 4];
        int r1 = ip[k * 4 + 4];
        uint2 u = *(const uint2*)(h_bf + (size_t)r0 * 64 + off * 4);
        uint2 v = *(const uint2*)(h_bf + (size_t)r1 * 64 + off * 4);
        a0 += lo2f(u.x); a1 += hi2f(u.x); a2 += lo2f(u.y); a3 += hi2f(u.y);
        a0 += lo2f(v.x); a1 += hi2f(v.x); a2 += lo2f(v.y); a3 += hi2f(v.y);
    }
    if (k < nq) {
        int r0 = ip[k * 4];
        uint2 u = *(const uint2*)(h_bf + (size_t)r0 * 64 + off * 4);
        a0 += lo2f(u.x); a1 += hi2f(u.x); a2 += lo2f(u.y); a3 += hi2f(u.y);
    }
#pragma unroll
    for (int m = 16; m <= 32; m <<= 1) {
        a0 += __shfl_xor(a0, m); a1 += __shfl_xor(a1, m);
        a2 += __shfl_xor(a2, m); a3 += __shfl_xor(a3, m);
    }
    if (t < 16) {
        uint2 d;
        d.x = ((unsigned)f2bf(a1) << 16) | f2bf(a0);
        d.y = ((unsigned)f2bf(a3) << 16) | f2bf(a2);
        *(uint2*)(agg_bf + (size_t)w * 64 + t * 4) = d;
    }
}

// ---------------------------------------------------------------------------
// MFMA tail, grid-stride persistent. Weights arrive pre-converted as bf16
// fragment arrays; staging is a plain uint4 copy (no per-block f32 converts).
__global__ __launch_bounds__(256) void k_tail(const ushort_t* __restrict__ h_bf,
                                              const ushort_t* __restrict__ agg_bf,
                                              const ushort_t* __restrict__ wrelF_g,
                                              const ushort_t* __restrict__ wrootF_g,
                                              const ushort_t* __restrict__ w2F_g,
                                              const float* __restrict__ brel,
                                              const float* __restrict__ b2,
                                              float* __restrict__ out,
                                              int N, int ntiles) {
    __shared__ alignas(16) ushort_t WrelF[8 * 512];
    __shared__ alignas(16) ushort_t WrootF[8 * 512];
    __shared__ alignas(16) ushort_t W2F[2 * 512];
    __shared__ alignas(16) ushort_t h2T[4][16 * 72];
    __shared__ float brelS[64];
    __shared__ float b2S[16];
    int tid = threadIdx.x;
    for (int i = tid; i < 512; i += 256) {
        ((uint4*)WrelF)[i]  = ((const uint4*)wrelF_g)[i];
        ((uint4*)WrootF)[i] = ((const uint4*)wrootF_g)[i];
    }
    for (int i = tid; i < 128; i += 256) ((uint4*)W2F)[i] = ((const uint4*)w2F_g)[i];
    if (tid < 64) brelS[tid] = brel[tid];
    if (tid < 16) b2S[tid] = b2[tid];
    __syncthreads();

    int lane = tid & 63;
    int wv = tid >> 6;
    int lrow = lane & 15;
    int lkg = lane >> 4;
    const bf16x8v* WrelV  = (const bf16x8v*)WrelF;
    const bf16x8v* WrootV = (const bf16x8v*)WrootF;
    const bf16x8v* W2V    = (const bf16x8v*)W2F;
    ushort_t* myT = h2T[wv];

    for (int tile = blockIdx.x * 4 + wv; tile < ntiles; tile += gridDim.x * 4) {
        int rbase = tile * 16;
        int arow = rbase + lrow; if (arow >= N) arow = N - 1;
        const bf16x8v* aggV = (const bf16x8v*)(agg_bf + (size_t)arow * 64);
        const bf16x8v* hV   = (const bf16x8v*)(h_bf + (size_t)arow * 64);
        bf16x8v a0 = aggV[lkg], a1 = aggV[4 + lkg];
        bf16x8v x0 = hV[lkg],   x1 = hV[4 + lkg];

        f32x4 acc[4];
#pragma unroll
        for (int nt = 0; nt < 4; ++nt) { acc[nt] = (f32x4){0.f, 0.f, 0.f, 0.f}; }
#pragma unroll
        for (int nt = 0; nt < 4; ++nt) {
            acc[nt] = __builtin_amdgcn_mfma_f32_16x16x32_bf16(a0, WrelV[(0 * 4 + nt) * 64 + lane], acc[nt], 0, 0, 0);
            acc[nt] = __builtin_amdgcn_mfma_f32_16x16x32_bf16(a1, WrelV[(1 * 4 + nt) * 64 + lane], acc[nt], 0, 0, 0);
            acc[nt] = __builtin_amdgcn_mfma_f32_16x16x32_bf16(x0, WrootV[(0 * 4 + nt) * 64 + lane], acc[nt], 0, 0, 0);
            acc[nt] = __builtin_amdgcn_mfma_f32_16x16x32_bf16(x1, WrootV[(1 * 4 + nt) * 64 + lane], acc[nt], 0, 0, 0);
        }
#pragma unroll
        for (int nt = 0; nt < 4; ++nt) {
            int feat = nt * 16 + lrow;
            float bias = brelS[feat];
#pragma unroll
            for (int r = 0; r < 4; ++r) {
                int noderow = lkg * 4 + r;
                myT[noderow * 72 + feat] = f2bf(tanhf(acc[nt][r] + bias));
            }
        }
        __threadfence_block();
        const bf16x8v* h2V = (const bf16x8v*)myT;
        bf16x8v p0 = h2V[lrow * 9 + lkg];
        bf16x8v p1 = h2V[lrow * 9 + 4 + lkg];
        f32x4 acc2 = (f32x4){0.f, 0.f, 0.f, 0.f};
        acc2 = __builtin_amdgcn_mfma_f32_16x16x32_bf16(p0, W2V[0 * 64 + lane], acc2, 0, 0, 0);
        acc2 = __builtin_amdgcn_mfma_f32_16x16x32_bf16(p1, W2V[1 * 64 + lane], acc2, 0, 0, 0);

        int feat = lrow;
        float bias2 = b2S[feat];
#pragma unroll
        for (int r = 0; r < 4; ++r) {
            int node = rbase + lkg * 4 + r;
            float o = tanhf(acc2[r] + bias2);
            if (feat >= 8) {
                float sp = log1pf(expf(o + SP_BIAS));
                o = fmaxf(sp, 1e-4f);
            }
            if (node < N) out[(size_t)feat * N + node] = o;
        }
        __threadfence_block();   // h2T reuse next iteration (same wave)
    }
}

// ---------------------------------------------------------------------------
extern "C" void kernel_launch(void* const* d_in, const int* in_sizes, int n_in,
                              void* d_out, int out_size, void* d_ws, size_t ws_size,
                              hipStream_t stream) {
    const float* x    = (const float*)d_in[0];
    const int*   ei   = (const int*)d_in[1];
    const float* W1   = (const float*)d_in[2];
    const float* b1   = (const float*)d_in[3];
    const float* Wrel = (const float*)d_in[4];
    const float* brel = (const float*)d_in[5];
    const float* Wroot= (const float*)d_in[6];
    const float* W2   = (const float*)d_in[7];
    const float* b2   = (const float*)d_in[8];

    int N = in_sizes[0] / 27;
    int E = in_sizes[1] / 2;

    int NB = (N + LB - 1) / LB;     // buckets of 512 dsts

    ushort_t* h_bf       = (ushort_t*)d_ws;                  // (N+1)*64 bf16
    ushort_t* agg_bf     = h_bf + (size_t)(N + 1) * 64;      // N*64 bf16
    ushort_t* wrelF_g    = agg_bf + (size_t)N * 64;          // 4096 bf16
    ushort_t* wrootF_g   = wrelF_g + 4096;                   // 4096 bf16
    ushort_t* w2F_g      = wrootF_g + 4096;                  // 1024 bf16
    int*      bucketArr  = (int*)(w2F_g + 1024);             // NB*LCAP int
    int*      src_padded = bucketArr + (size_t)NB * LCAP;    // NB*PCAP int
    int*      pstart     = src_padded + (size_t)NB * PCAP;   // N int
    int*      pdeg       = pstart + N;                       // N int
    int*      bucketCnt  = pdeg + N;                         // NB int
    int*      is32       = bucketCnt + NB;                   // 1 int

    int ntiles16 = (N + 15) / 16;
    int nchunks4 = (N + 3) / 4;

    int ncheck = E < 8192 ? E : 8192;
    k_init<<<37, 256, 0, stream>>>(ei, ncheck, is32, bucketCnt, NB,
                                   (int*)(h_bf + (size_t)N * 64),
                                   Wrel, Wroot, W2, wrelF_g, wrootF_g, w2F_g);
    k_lin1<<<2048, 256, 0, stream>>>(x, W1, b1, h_bf, N, nchunks4);
    k_bin<<<(E + EPB - 1) / EPB, 256, 0, stream>>>(ei, is32, bucketCnt, bucketArr,
                                                   E, NB);
    k_local<<<NB, 256, 0, stream>>>(bucketArr, bucketCnt, src_padded,
                                    pstart, pdeg, N);
    k_agg<<<nchunks4, 256, 0, stream>>>(h_bf, src_padded, pstart, pdeg,
                                        agg_bf, N);
    int tgrid = (ntiles16 + 3) / 4; if (tgrid > 1024) tgrid = 1024;
    k_tail<<<tgrid, 256, 0, stream>>>(h_bf, agg_bf, wrelF_g, wrootF_g, w2F_g,
                                      brel, b2, (float*)d_out, N, ntiles16);
}

// Round 10
// 126.940 us; speedup vs baseline: 6.2096x; 1.1137x over previous
//
#include <hip/hip_runtime.h>
#include <hip/hip_bf16.h>
#include <math.h>

typedef unsigned short ushort_t;
typedef float f32x4 __attribute__((ext_vector_type(4)));
typedef short bf16x8v __attribute__((ext_vector_type(8)));

static constexpr float SP_BIAS = 0.5413248546129181f; // log(expm1(1.0))
#define LB   512     // nodes per bucket (9-bit local index)
#define LCAP 12288   // max compact entries per bucket (mean 8163)
#define PCAP 16384   // fixed padded stride per bucket
#define MAXB 256     // max buckets -> N <= 131072 (17-bit src pack)
#define EPB  4096    // edges per bin block

__device__ __forceinline__ ushort_t f2bf(float f) {
    union { float f; unsigned u; } v; v.f = f;
    unsigned r = v.u + 0x7FFFu + ((v.u >> 16) & 1u);   // RNE
    return (ushort_t)(r >> 16);
}
__device__ __forceinline__ float bf2f(ushort_t u) {
    union { unsigned u; float f; } v; v.u = ((unsigned)u) << 16;
    return v.f;
}
__device__ __forceinline__ float hi2f(unsigned u) {
    union { unsigned u; float f; } v; v.u = u & 0xFFFF0000u;
    return v.f;
}
__device__ __forceinline__ float lo2f(unsigned u) {
    union { unsigned u; float f; } v; v.u = u << 16;
    return v.f;
}

// ---------------------------------------------------------------------------
// One-block init: zero bucketCnt + dummy h-row, set dummyIdx=N, detect
// int32 vs int64 edge layout.
__global__ __launch_bounds__(256) void k_init(const int* __restrict__ ei32,
                                              int n_check, int* __restrict__ is32,
                                              int* __restrict__ bucketCnt, int NB,
                                              int* __restrict__ dummyRow,
                                              int* __restrict__ dummyIdx, int N) {
    __shared__ int s;
    int tid = threadIdx.x;
    if (tid == 0) { s = 0; *dummyIdx = N; }
    for (int i = tid; i < NB; i += 256) bucketCnt[i] = 0;
    if (tid < 32) dummyRow[tid] = 0;
    __syncthreads();
    int found = 0;
    for (int i = tid; i < n_check; i += 256) {
        if (ei32[2 * i + 1] != 0) { found = 1; break; }
    }
    if (found) atomicOr(&s, 1);
    __syncthreads();
    if (tid == 0) *is32 = s;
}

// ---------------------------------------------------------------------------
// Fused independent-phase kernel, split by block range:
//   [0, GLIN)            : h_bf = bf16(x@W1+b1), persistent grid-stride
//   [GLIN, GLIN+GBIN)    : single-pass edge binning (LDS-staged)
//   [GLIN+GBIN, +36)     : Wrel/Wroot/W2 -> bf16 MFMA fragment arrays
__global__ __launch_bounds__(256) void k_fused1(
        const float* __restrict__ x, const float* __restrict__ W1,
        const float* __restrict__ b1, ushort_t* __restrict__ h_bf,
        int N, int nchunks, int GLIN,
        const int* __restrict__ ei, const int* __restrict__ is32,
        int* __restrict__ bucketCnt, int* __restrict__ bucketArr,
        int E, int NB, int GBIN,
        const float* __restrict__ Wrel, const float* __restrict__ Wroot,
        const float* __restrict__ W2, ushort_t* __restrict__ wrelF,
        ushort_t* __restrict__ wrootF, ushort_t* __restrict__ w2F) {
    __shared__ float Ws[27 * 64];
    __shared__ float bs[64];
    __shared__ float xs[4 * 27];
    __shared__ int hist[MAXB];
    __shared__ int cur[MAXB];
    __shared__ int s_dst[EPB];
    __shared__ int s_src[EPB];
    int bid = blockIdx.x, tid = threadIdx.x;
    if (bid < GLIN) {
        for (int i = tid; i < 27 * 64; i += 256) Ws[i] = W1[i];
        if (tid < 64) bs[tid] = b1[tid];
        int g = tid >> 6, t = tid & 63;
        for (int chunk = bid; chunk < nchunks; chunk += GLIN) {
            int base = chunk * 4;
            __syncthreads();
            if (tid < 108) {
                int gidx = base * 27 + tid;
                xs[tid] = (gidx < N * 27) ? x[gidx] : 0.f;
            }
            __syncthreads();
            int node = base + g;
            if (node < N) {
                float acc = bs[t];
                const float* xr = &xs[g * 27];
#pragma unroll
                for (int k = 0; k < 27; ++k) acc = fmaf(xr[k], Ws[k * 64 + t], acc);
                h_bf[(size_t)node * 64 + t] = f2bf(acc);
            }
        }
    } else if (bid < GLIN + GBIN) {
        int bb = bid - GLIN;
        for (int i = tid; i < NB; i += 256) hist[i] = 0;
        __syncthreads();
        int e0 = bb * EPB;
        int cnt = E - e0; if (cnt > EPB) cnt = EPB;
        if (*is32) {
            for (int i = tid; i < cnt; i += 256) {
                s_src[i] = ei[e0 + i];
                s_dst[i] = ei[E + e0 + i];
            }
        } else {
            const int2* p = (const int2*)ei;
            for (int i = tid; i < cnt; i += 256) {
                s_src[i] = p[e0 + i].x;
                s_dst[i] = p[E + e0 + i].x;
            }
        }
        __syncthreads();
        for (int i = tid; i < cnt; i += 256) atomicAdd(&hist[s_dst[i] >> 9], 1);
        __syncthreads();
        for (int b = tid; b < NB; b += 256) {
            int c = hist[b];
            if (c > 0) cur[b] = b * LCAP + atomicAdd(&bucketCnt[b], c);
        }
        __syncthreads();
        for (int i = tid; i < cnt; i += 256) {
            int d = s_dst[i];
            int b = d >> 9;
            int slot = atomicAdd(&cur[b], 1);
            if (slot < (b + 1) * LCAP)
                bucketArr[slot] = ((d & 511) << 17) | s_src[i];
        }
    } else {
        int wb = bid - GLIN - GBIN;     // 0..35
        if (wb < 32) {
            int i = (wb & 15) * 256 + tid;
            int j = i & 7, lane = (i >> 3) & 63, grp = i >> 9;
            int kt = grp >> 2, nt = grp & 3;
            int k = (kt << 5) + ((lane >> 4) << 3) + j;
            int n = (nt << 4) + (lane & 15);
            if (wb < 16) wrelF[i]  = f2bf(Wrel[k * 64 + n]);
            else         wrootF[i] = f2bf(Wroot[k * 64 + n]);
        } else {
            int i = (wb - 32) * 256 + tid;
            int j = i & 7, lane = (i >> 3) & 63, kt = i >> 9;
            int k = (kt << 5) + ((lane >> 4) << 3) + j;
            int n = (lane & 15);
            w2F[i] = f2bf(W2[k * 16 + n]);
        }
    }
}

// ---------------------------------------------------------------------------
// Per-bucket LDS counting sort -> PADDED CSR segment at fixed stride PCAP.
// Rows padded to multiple of 8 entries; pads point at dummy row N (zeros).
__global__ __launch_bounds__(256) void k_local(const int* __restrict__ bucketArr,
                                               const int* __restrict__ bucketCnt,
                                               int* __restrict__ src_padded,
                                               int* __restrict__ pstart,
                                               int* __restrict__ pdeg,
                                               int N) {
    __shared__ int hist[LB];
    __shared__ int cstart[LB];
    __shared__ int cursor[LB];
    __shared__ int ppos[LB];
    __shared__ int sdata[256];
    __shared__ int sorted[LCAP];
    int b = blockIdx.x, tid = threadIdx.x;
    for (int i = tid; i < LB; i += 256) hist[i] = 0;
    __syncthreads();
    int cnt = bucketCnt[b];
    if (cnt > LCAP) cnt = LCAP;
    const int* arr = bucketArr + (size_t)b * LCAP;
    for (int i = tid; i < cnt; i += 256) atomicAdd(&hist[arr[i] >> 17], 1);
    __syncthreads();
    int v0 = hist[2 * tid], v1 = hist[2 * tid + 1];
    int psum = v0 + v1;
    sdata[tid] = psum;
    __syncthreads();
    for (int off = 1; off < 256; off <<= 1) {
        int add = (tid >= off) ? sdata[tid - off] : 0;
        __syncthreads();
        sdata[tid] += add;
        __syncthreads();
    }
    int cexcl = sdata[tid] - psum;
    cstart[2 * tid] = cexcl;           cursor[2 * tid] = cexcl;
    cstart[2 * tid + 1] = cexcl + v0;  cursor[2 * tid + 1] = cexcl + v0;
    int p0 = (v0 + 7) & ~7, p1 = (v1 + 7) & ~7;
    int ppsum = p0 + p1;
    __syncthreads();
    sdata[tid] = ppsum;
    __syncthreads();
    for (int off = 1; off < 256; off <<= 1) {
        int add = (tid >= off) ? sdata[tid - off] : 0;
        __syncthreads();
        sdata[tid] += add;
        __syncthreads();
    }
    int pexcl = sdata[tid] - ppsum;
    ppos[2 * tid] = pexcl;
    ppos[2 * tid + 1] = pexcl + p0;
    __syncthreads();
    for (int i = tid; i < cnt; i += 256) {
        int pk = arr[i];
        int pos = atomicAdd(&cursor[pk >> 17], 1);
        sorted[pos] = pk & 0x1FFFF;
    }
    __syncthreads();
    int* outp = src_padded + (size_t)b * PCAP;
    int n0 = b * LB;
    for (int ln = tid; ln < LB; ln += 256) {
        int h = hist[ln], cs = cstart[ln], pp = ppos[ln];
        int ph = (h + 7) & ~7;
        for (int j = 0; j < h; ++j) outp[pp + j] = sorted[cs + j];
        for (int j = h; j < ph; ++j) outp[pp + j] = N;
        int node = n0 + ln;
        if (node < N) {
            pstart[node] = b * PCAP + pp;
            pdeg[node] = ph >> 3;        // octet count
        }
    }
}

// ---------------------------------------------------------------------------
// agg gather, 2 nodes per wave. Quad scheme (lane t: row sub=t>>4, 8B chunk
// off=t&15; one dwordx2 covers 4 rows). Both nodes' chains interleaved
// branchlessly (short chain reads dummy idx -> zero row N) -> 4 independent
// gathers in flight per wave.
__global__ __launch_bounds__(256) void k_agg(const ushort_t* __restrict__ h_bf,
                                             const int* __restrict__ src_padded,
                                             const int* __restrict__ pstart,
                                             const int* __restrict__ pdeg,
                                             const int* __restrict__ dummyIdx,
                                             ushort_t* __restrict__ agg_bf, int N) {
    int w = (blockIdx.x * 256 + threadIdx.x) >> 6;
    int t = threadIdx.x & 63;
    int nA = 2 * w, nB = 2 * w + 1;
    if (nA >= N) return;
    int sub = t >> 4, off = t & 15;
    int stA = pstart[nA];
    int nqA = pdeg[nA] * 2;
    int hasB = (nB < N);
    int stB = hasB ? pstart[nB] : stA;
    int nqB = hasB ? pdeg[nB] * 2 : 0;
    const int* ipA = src_padded + stA + sub;
    const int* ipB = src_padded + stB + sub;
    float a0 = 0.f, a1 = 0.f, a2 = 0.f, a3 = 0.f;
    float b0 = 0.f, b1 = 0.f, b2 = 0.f, b3 = 0.f;
    int nq = nqA > nqB ? nqA : nqB;
    for (int k = 0; k < nq; k += 2) {
        const int* pA0 = (k     < nqA) ? ipA + k * 4     : dummyIdx;
        const int* pA1 = (k + 1 < nqA) ? ipA + k * 4 + 4 : dummyIdx;
        const int* pB0 = (k     < nqB) ? ipB + k * 4     : dummyIdx;
        const int* pB1 = (k + 1 < nqB) ? ipB + k * 4 + 4 : dummyIdx;
        int rA0 = *pA0, rA1 = *pA1, rB0 = *pB0, rB1 = *pB1;
        uint2 uA0 = *(const uint2*)(h_bf + (size_t)rA0 * 64 + off * 4);
        uint2 uA1 = *(const uint2*)(h_bf + (size_t)rA1 * 64 + off * 4);
        uint2 uB0 = *(const uint2*)(h_bf + (size_t)rB0 * 64 + off * 4);
        uint2 uB1 = *(const uint2*)(h_bf + (size_t)rB1 * 64 + off * 4);
        a0 += lo2f(uA0.x); a1 += hi2f(uA0.x); a2 += lo2f(uA0.y); a3 += hi2f(uA0.y);
        a0 += lo2f(uA1.x); a1 += hi2f(uA1.x); a2 += lo2f(uA1.y); a3 += hi2f(uA1.y);
        b0 += lo2f(uB0.x); b1 += hi2f(uB0.x); b2 += lo2f(uB0.y); b3 += hi2f(uB0.y);
        b0 += lo2f(uB1.x); b1 += hi2f(uB1.x); b2 += lo2f(uB1.y); b3 += hi2f(uB1.y);
    }
#pragma unroll
    for (int m = 16; m <= 32; m <<= 1) {
        a0 += __shfl_xor(a0, m); a1 += __shfl_xor(a1, m);
        a2 += __shfl_xor(a2, m); a3 += __shfl_xor(a3, m);
        b0 += __shfl_xor(b0, m); b1 += __shfl_xor(b1, m);
        b2 += __shfl_xor(b2, m); b3 += __shfl_xor(b3, m);
    }
    if (t < 16) {
        uint2 d;
        d.x = ((unsigned)f2bf(a1) << 16) | f2bf(a0);
        d.y = ((unsigned)f2bf(a3) << 16) | f2bf(a2);
        *(uint2*)(agg_bf + (size_t)nA * 64 + off * 4) = d;
    } else if (t < 32 && hasB) {
        uint2 d;
        d.x = ((unsigned)f2bf(b1) << 16) | f2bf(b0);
        d.y = ((unsigned)f2bf(b3) << 16) | f2bf(b2);
        *(uint2*)(agg_bf + (size_t)nB * 64 + off * 4) = d;
    }
}

// ---------------------------------------------------------------------------
// MFMA tail, grid-stride persistent; weights arrive pre-converted bf16 frags.
__global__ __launch_bounds__(256) void k_tail(const ushort_t* __restrict__ h_bf,
                                              const ushort_t* __restrict__ agg_bf,
                                              const ushort_t* __restrict__ wrelF_g,
                                              const ushort_t* __restrict__ wrootF_g,
                                              const ushort_t* __restrict__ w2F_g,
                                              const float* __restrict__ brel,
                                              const float* __restrict__ b2,
                                              float* __restrict__ out,
                                              int N, int ntiles) {
    __shared__ alignas(16) ushort_t WrelF[8 * 512];
    __shared__ alignas(16) ushort_t WrootF[8 * 512];
    __shared__ alignas(16) ushort_t W2F[2 * 512];
    __shared__ alignas(16) ushort_t h2T[4][16 * 72];
    __shared__ float brelS[64];
    __shared__ float b2S[16];
    int tid = threadIdx.x;
    for (int i = tid; i < 512; i += 256) {
        ((uint4*)WrelF)[i]  = ((const uint4*)wrelF_g)[i];
        ((uint4*)WrootF)[i] = ((const uint4*)wrootF_g)[i];
    }
    for (int i = tid; i < 128; i += 256) ((uint4*)W2F)[i] = ((const uint4*)w2F_g)[i];
    if (tid < 64) brelS[tid] = brel[tid];
    if (tid < 16) b2S[tid] = b2[tid];
    __syncthreads();

    int lane = tid & 63;
    int wv = tid >> 6;
    int lrow = lane & 15;
    int lkg = lane >> 4;
    const bf16x8v* WrelV  = (const bf16x8v*)WrelF;
    const bf16x8v* WrootV = (const bf16x8v*)WrootF;
    const bf16x8v* W2V    = (const bf16x8v*)W2F;
    ushort_t* myT = h2T[wv];

    for (int tile = blockIdx.x * 4 + wv; tile < ntiles; tile += gridDim.x * 4) {
        int rbase = tile * 16;
        int arow = rbase + lrow; if (arow >= N) arow = N - 1;
        const bf16x8v* aggV = (const bf16x8v*)(agg_bf + (size_t)arow * 64);
        const bf16x8v* hV   = (const bf16x8v*)(h_bf + (size_t)arow * 64);
        bf16x8v a0 = aggV[lkg], a1 = aggV[4 + lkg];
        bf16x8v x0 = hV[lkg],   x1 = hV[4 + lkg];

        f32x4 acc[4];
#pragma unroll
        for (int nt = 0; nt < 4; ++nt) { acc[nt] = (f32x4){0.f, 0.f, 0.f, 0.f}; }
#pragma unroll
        for (int nt = 0; nt < 4; ++nt) {
            acc[nt] = __builtin_amdgcn_mfma_f32_16x16x32_bf16(a0, WrelV[(0 * 4 + nt) * 64 + lane], acc[nt], 0, 0, 0);
            acc[nt] = __builtin_amdgcn_mfma_f32_16x16x32_bf16(a1, WrelV[(1 * 4 + nt) * 64 + lane], acc[nt], 0, 0, 0);
            acc[nt] = __builtin_amdgcn_mfma_f32_16x16x32_bf16(x0, WrootV[(0 * 4 + nt) * 64 + lane], acc[nt], 0, 0, 0);
            acc[nt] = __builtin_amdgcn_mfma_f32_16x16x32_bf16(x1, WrootV[(1 * 4 + nt) * 64 + lane], acc[nt], 0, 0, 0);
        }
#pragma unroll
        for (int nt = 0; nt < 4; ++nt) {
            int feat = nt * 16 + lrow;
            float bias = brelS[feat];
#pragma unroll
            for (int r = 0; r < 4; ++r) {
                int noderow = lkg * 4 + r;
                myT[noderow * 72 + feat] = f2bf(tanhf(acc[nt][r] + bias));
            }
        }
        __threadfence_block();
        const bf16x8v* h2V = (const bf16x8v*)myT;
        bf16x8v p0 = h2V[lrow * 9 + lkg];
        bf16x8v p1 = h2V[lrow * 9 + 4 + lkg];
        f32x4 acc2 = (f32x4){0.f, 0.f, 0.f, 0.f};
        acc2 = __builtin_amdgcn_mfma_f32_16x16x32_bf16(p0, W2V[0 * 64 + lane], acc2, 0, 0, 0);
        acc2 = __builtin_amdgcn_mfma_f32_16x16x32_bf16(p1, W2V[1 * 64 + lane], acc2, 0, 0, 0);

        int feat = lrow;
        float bias2 = b2S[feat];
#pragma unroll
        for (int r = 0; r < 4; ++r) {
            int node = rbase + lkg * 4 + r;
            float o = tanhf(acc2[r] + bias2);
            if (feat >= 8) {
                float sp = log1pf(expf(o + SP_BIAS));
                o = fmaxf(sp, 1e-4f);
            }
            if (node < N) out[(size_t)feat * N + node] = o;
        }
        __threadfence_block();   // h2T reuse next iteration (same wave)
    }
}

// ---------------------------------------------------------------------------
extern "C" void kernel_launch(void* const* d_in, const int* in_sizes, int n_in,
                              void* d_out, int out_size, void* d_ws, size_t ws_size,
                              hipStream_t stream) {
    const float* x    = (const float*)d_in[0];
    const int*   ei   = (const int*)d_in[1];
    const float* W1   = (const float*)d_in[2];
    const float* b1   = (const float*)d_in[3];
    const float* Wrel = (const float*)d_in[4];
    const float* brel = (const float*)d_in[5];
    const float* Wroot= (const float*)d_in[6];
    const float* W2   = (const float*)d_in[7];
    const float* b2   = (const float*)d_in[8];

    int N = in_sizes[0] / 27;
    int E = in_sizes[1] / 2;

    int NB = (N + LB - 1) / LB;     // buckets of 512 dsts

    ushort_t* h_bf       = (ushort_t*)d_ws;                  // (N+1)*64 bf16
    ushort_t* agg_bf     = h_bf + (size_t)(N + 1) * 64;      // N*64 bf16
    ushort_t* wrelF_g    = agg_bf + (size_t)N * 64;          // 4096 bf16
    ushort_t* wrootF_g   = wrelF_g + 4096;                   // 4096 bf16
    ushort_t* w2F_g      = wrootF_g + 4096;                  // 1024 bf16
    int*      bucketArr  = (int*)(w2F_g + 1024);             // NB*LCAP int
    int*      src_padded = bucketArr + (size_t)NB * LCAP;    // NB*PCAP int
    int*      pstart     = src_padded + (size_t)NB * PCAP;   // N int
    int*      pdeg       = pstart + N;                       // N int
    int*      bucketCnt  = pdeg + N;                         // NB int
    int*      is32       = bucketCnt + NB;                   // 1 int
    int*      dummyIdx   = is32 + 1;                         // 1 int

    int ntiles16 = (N + 15) / 16;
    int nchunks4 = (N + 3) / 4;
    int GLIN = 2048;
    int GBIN = (E + EPB - 1) / EPB;

    int ncheck = E < 8192 ? E : 8192;
    k_init<<<1, 256, 0, stream>>>(ei, ncheck, is32, bucketCnt, NB,
                                  (int*)(h_bf + (size_t)N * 64), dummyIdx, N);
    k_fused1<<<GLIN + GBIN + 36, 256, 0, stream>>>(
        x, W1, b1, h_bf, N, nchunks4, GLIN,
        ei, is32, bucketCnt, bucketArr, E, NB, GBIN,
        Wrel, Wroot, W2, wrelF_g, wrootF_g, w2F_g);
    k_local<<<NB, 256, 0, stream>>>(bucketArr, bucketCnt, src_padded,
                                    pstart, pdeg, N);
    int nwaves2 = (N + 1) / 2;
    k_agg<<<(nwaves2 + 3) / 4, 256, 0, stream>>>(h_bf, src_padded, pstart, pdeg,
                                                 dummyIdx, agg_bf, N);
    int tgrid = (ntiles16 + 3) / 4; if (tgrid > 1024) tgrid = 1024;
    k_tail<<<tgrid, 256, 0, stream>>>(h_bf, agg_bf, wrelF_g, wrootF_g, w2F_g,
                                      brel, b2, (float*)d_out, N, ntiles16);
}